// Round 9
// baseline (6114.939 us; speedup 1.0000x reference)
//
#include <hip/hip_runtime.h>
#include <hip/hip_bf16.h>
#include <math.h>

#define DI __device__ __forceinline__
#define AS1 __attribute__((address_space(1)))
#define AS3 __attribute__((address_space(3)))

static constexpr int  B_ = 4, C_ = 256, N_ = 1024, L_ = 12, BL_ = 48;
static constexpr long SLAB = (long)N_ * C_;          // 262144 elems per (b,l)
static constexpr long TOT  = (long)BL_ * SLAB;       // 12,582,912 elems

typedef __attribute__((ext_vector_type(8))) short bf16x8;
typedef __attribute__((ext_vector_type(4))) float f32x4;

DI float b2f(uint hw) { return __builtin_bit_cast(float, (hw & 0xffffu) << 16); }
DI ushort f2b(float f) {
    uint u = __builtin_bit_cast(uint, f);
    u += 0x7FFFu + ((u >> 16) & 1u);
    return (ushort)(u >> 16);
}
DI uint pack2(float a, float b) {
    __hip_bfloat162 h = __float22bfloat162_rn(make_float2(a, b));
    uint r;
    __builtin_memcpy(&r, &h, 4);
    return r;
}

DI void gload16(const void* g, void* l) {
    __builtin_amdgcn_global_load_lds((AS1 uint*)g, (AS3 uint*)l, 16, 0, 0);
}

// ---------------- block reductions (256 threads, 4 waves) ----------------
DI float block_sum256(float v, float* sc) {
    #pragma unroll
    for (int o = 32; o > 0; o >>= 1) v += __shfl_xor(v, o, 64);
    int wid = threadIdx.x >> 6;
    __syncthreads();
    if ((threadIdx.x & 63) == 0) sc[wid] = v;
    __syncthreads();
    return sc[0] + sc[1] + sc[2] + sc[3];
}
DI float block_max256(float v, float* sc) {
    #pragma unroll
    for (int o = 32; o > 0; o >>= 1) v = fmaxf(v, __shfl_xor(v, o, 64));
    int wid = threadIdx.x >> 6;
    __syncthreads();
    if ((threadIdx.x & 63) == 0) sc[wid] = v;
    __syncthreads();
    return fmaxf(fmaxf(sc[0], sc[1]), fmaxf(sc[2], sc[3]));
}

// ---------------- adp = softmax(relu(nv1@nv2), axis=1), bf16 out ----------------
__global__ __launch_bounds__(256) void k_adp(const float* __restrict__ nv1,
                                             const float* __restrict__ nv2,
                                             ushort* __restrict__ adp) {
    __shared__ float r[6];
    __shared__ float sc[4];
    int row = blockIdx.x, tid = threadIdx.x;
    if (tid < 6) r[tid] = nv1[row * 6 + tid];
    __syncthreads();
    float e[4];
    #pragma unroll
    for (int q = 0; q < 4; q++) {
        int j = tid + q * 256;
        float s = 0.f;
        #pragma unroll
        for (int k = 0; k < 6; k++) s += r[k] * nv2[k * 1024 + j];
        e[q] = s > 0.f ? s : 0.f;
    }
    float m = fmaxf(fmaxf(e[0], e[1]), fmaxf(e[2], e[3]));
    m = block_max256(m, sc);
    float ps = 0.f;
    #pragma unroll
    for (int q = 0; q < 4; q++) { e[q] = __expf(e[q] - m); ps += e[q]; }
    ps = block_sum256(ps, sc);
    float rinv = 1.f / ps;
    #pragma unroll
    for (int q = 0; q < 4; q++) adp[(long)row * 1024 + tid + q * 256] = f2b(e[q] * rinv);
}

// ------- transpose in: x[b][c][n][l] -> Xb[(b*12+l)][n][c] bf16 + fp32 copy -------
__global__ __launch_bounds__(256) void k_tin(const float* __restrict__ x,
                                             ushort* __restrict__ xb,
                                             float* __restrict__ xf) {
    __shared__ float t[64][65];
    int nl0 = blockIdx.x * 64, c0 = blockIdx.y * 64, b = blockIdx.z;
    int lx = threadIdx.x & 63, ly = threadIdx.x >> 6;
    #pragma unroll
    for (int i = 0; i < 16; i++) {
        int c = c0 + ly + i * 4;
        t[ly + i * 4][lx] = x[(long)(b * 256 + c) * 12288 + nl0 + lx];
    }
    __syncthreads();
    #pragma unroll
    for (int i = 0; i < 16; i++) {
        int nl = nl0 + ly + i * 4;
        int n = nl / 12, l = nl % 12;
        long idx = ((long)(b * 12 + l) * 1024 + n) * 256 + c0 + lx;
        float v = t[lx][ly + i * 4];
        xb[idx] = f2b(v);
        xf[idx] = v;
    }
}

// ---------------- per-bl transpose Xb[n][c] -> XTT[c][n] (bf16) ----------------
__global__ __launch_bounds__(256) void k_xtt(const ushort* __restrict__ X,
                                             ushort* __restrict__ XT) {
    __shared__ ushort t[64][68];
    int bl = blockIdx.z;
    int n0 = blockIdx.x * 64, c0 = blockIdx.y * 64;
    int lx = threadIdx.x & 63, ly = threadIdx.x >> 6;
    const ushort* Xp = X + (long)bl * SLAB;
    #pragma unroll
    for (int i = 0; i < 16; i++)
        t[ly + i * 4][lx] = Xp[(long)(n0 + ly + i * 4) * 256 + c0 + lx];
    __syncthreads();
    ushort* Tp = XT + (long)bl * SLAB;
    #pragma unroll
    for (int i = 0; i < 16; i++)
        Tp[(long)(c0 + ly + i * 4) * 1024 + n0 + lx] = t[lx][ly + i * 4];
}

// -------- GAT weight transposes 256x256 fp32 [c][o] -> bf16 [o][c] --------
__global__ __launch_bounds__(256) void k_wt2(const float* __restrict__ S0, ushort* __restrict__ D0,
                                             const float* __restrict__ S1, ushort* __restrict__ D1) {
    __shared__ float t[64][65];
    const float* S = blockIdx.z ? S1 : S0;
    ushort* D = blockIdx.z ? D1 : D0;
    int c0 = blockIdx.x * 64, o0 = blockIdx.y * 64;
    int lx = threadIdx.x & 63, ly = threadIdx.x >> 6;
    #pragma unroll
    for (int i = 0; i < 16; i++)
        t[ly + i * 4][lx] = S[(long)(c0 + ly + i * 4) * 256 + o0 + lx];
    __syncthreads();
    #pragma unroll
    for (int i = 0; i < 16; i++)
        D[(long)(o0 + ly + i * 4) * 256 + c0 + lx] = f2b(t[lx][ly + i * 4]);
}

// ---------------- fp32 -> bf16 straight cast ----------------
__global__ __launch_bounds__(256) void k_wconv(const float* __restrict__ S, ushort* __restrict__ D) {
    long i = (long)blockIdx.x * 256 + threadIdx.x;
    D[i] = f2b(S[i]);
}

// ------- interleaved GLU weights: WGI[p*32+q] = (q<16 ? Wg1 : Wg2) row p*16+q%16 -------
__global__ __launch_bounds__(256) void k_wgi(const float* __restrict__ W1, const float* __restrict__ b1,
                                             const float* __restrict__ W2, const float* __restrict__ b2,
                                             ushort* __restrict__ WGI, float* __restrict__ BI) {
    int n = blockIdx.x, p = n >> 5, q = n & 31;
    const float* src = (q < 16) ? W1 + (long)(p * 16 + q) * 256
                                : W2 + (long)(p * 16 + q - 16) * 256;
    WGI[(long)n * 256 + threadIdx.x] = f2b(src[threadIdx.x]);
    if (threadIdx.x == 0) BI[n] = (q < 16) ? b1[p * 16 + q] : b2[p * 16 + q - 16];
}

// ----- va = W @ a pair -----
__global__ __launch_bounds__(256) void k_va(const float* __restrict__ W, const float* __restrict__ a,
                                            float* __restrict__ va) {
    __shared__ float sc[4];
    int c = blockIdx.x, t = threadIdx.x;
    float w = W[(long)c * 256 + t];
    float s1 = block_sum256(w * a[t], sc);
    float s2 = block_sum256(w * a[256 + t], sc);
    if (t == 0) { va[c] = s1; va[256 + c] = s2; }
}

// ------- weight/bias prep: wt[n][c] = w[c][n]+1, bt[n][c] = b[c][n] -------
__global__ __launch_bounds__(256) void k_wtprep(const float* __restrict__ w,
                                                const float* __restrict__ b,
                                                float* __restrict__ wt,
                                                float* __restrict__ bt) {
    int n = blockIdx.x, c = threadIdx.x;
    wt[(long)n * 256 + c] = w[(long)c * 1024 + n] + 1.f;
    bt[(long)n * 256 + c] = b[(long)c * 1024 + n];
}

// ------- pack mask bits -------
__global__ __launch_bounds__(256) void k_maskpack(const int* __restrict__ dg,
                                                  uint* __restrict__ maskw) {
    int w = blockIdx.x * 256 + threadIdx.x;
    int row = w >> 5, wo = w & 31;
    uint m = 0;
    #pragma unroll
    for (int b = 0; b < 32; b++)
        m |= (dg[(long)row * 1024 + wo * 32 + b] > 0 ? 1u : 0u) << b;
    maskw[w] = m;
}

// ------- bf16 MFMA GEMM, 2-phase pipelined -------
// GLU=0: plain (+bias) -> Cf/Cb. GLU=1: interleaved g1/g2, h=g1*sig(g2) -> Cb.
// GLU=2: finpre fusion: v=(acc+bias + (FA-m1)*r1)*WTp + BTp -> Cf, + LN partials.
template<int NPAIR, int GLU>
__global__ __launch_bounds__(256) void k_bgemm(
    const ushort* __restrict__ A0, long sA0,
    const ushort* __restrict__ A1, long sA1,
    int lda, int K0, int KK,
    const ushort* __restrict__ Bt, long sBt,
    const float* __restrict__ bias,
    float* __restrict__ Cf, ushort* __restrict__ Cb, long sC,
    const float* __restrict__ biasi,
    const float* __restrict__ FA, const float2* __restrict__ ST1,
    const float* __restrict__ WTp, const float* __restrict__ BTp,
    float2* __restrict__ partOut) {
    __shared__ ushort As[2][128 * 32];
    __shared__ ushort Bs[2][128 * 32];
    __shared__ float sc[4];
    const int tid = threadIdx.x;
    const int bl = blockIdx.z;
    const int m0 = blockIdx.x * 128, n0 = blockIdx.y * 128;
    const int N = gridDim.y * 128;
    const int lane = tid & 63, w = tid >> 6;
    const int wm = (w >> 1) * 64, wn = (w & 1) * 64;
    const int sr = tid >> 2, sk = (tid & 3) * 8;
    const int fr = lane & 15, fk = (lane >> 4) * 8;
    f32x4 acc[4][4] = {};
    const ushort* Ab0 = A0 + (long)bl * sA0;
    const ushort* Ab1 = (NPAIR == 2) ? A1 + (long)bl * sA1 : nullptr;
    const ushort* Bb = Bt + (long)bl * sBt;

    auto stage = [&](int buf, int k0) {
        const ushort* Asrc = Ab0; int kl = k0;
        if (NPAIR == 2 && k0 >= K0) { Asrc = Ab1; kl = k0 - K0; }
        gload16(&Asrc[(long)(m0 + sr) * lda + kl + sk],      &As[buf][sr * 32 + sk]);
        gload16(&Asrc[(long)(m0 + sr + 64) * lda + kl + sk], &As[buf][(sr + 64) * 32 + sk]);
        gload16(&Bb[(long)(n0 + sr) * KK + k0 + sk],         &Bs[buf][sr * 32 + sk]);
        gload16(&Bb[(long)(n0 + sr + 64) * KK + k0 + sk],    &Bs[buf][(sr + 64) * 32 + sk]);
    };
    auto compute = [&](int buf) {
        bf16x8 af[4], bg[4];
        #pragma unroll
        for (int i = 0; i < 4; i++) {
            af[i] = *(const bf16x8*)&As[buf][(wm + i * 16 + fr) * 32 + fk];
            bg[i] = *(const bf16x8*)&Bs[buf][(wn + i * 16 + fr) * 32 + fk];
        }
        #pragma unroll
        for (int i = 0; i < 4; i++)
            #pragma unroll
            for (int j = 0; j < 4; j++)
                acc[i][j] = __builtin_amdgcn_mfma_f32_16x16x32_bf16(af[i], bg[j], acc[i][j], 0, 0, 0);
    };

    stage(0, 0);
    __syncthreads();
    int cur = 0;
    for (int k0 = 32; k0 < KK; k0 += 32) {
        stage(cur ^ 1, k0);
        compute(cur);
        __syncthreads();
        cur ^= 1;
    }
    compute(cur);

    const int cn = lane & 15, rb = (lane >> 4) * 4;
    if (GLU == 1) {
        #pragma unroll
        for (int nt = 0; nt < 4; nt += 2) {
            int n1 = n0 + wn + nt * 16 + cn;
            int hcol = ((n1 >> 5) << 4) + cn;
            float b1 = biasi[n1], b2 = biasi[n1 + 16];
            #pragma unroll
            for (int i = 0; i < 4; i++) {
                #pragma unroll
                for (int r = 0; r < 4; r++) {
                    int m = m0 + wm + i * 16 + rb + r;
                    float g1 = acc[i][nt][r] + b1;
                    float g2 = acc[i][nt + 1][r] + b2;
                    float h = g1 / (1.f + __expf(-g2));
                    Cb[(long)bl * sC + (long)m * 256 + hcol] = f2b(h);
                }
            }
        }
    } else if (GLU == 2) {
        float2 st = ST1[bl];
        float ssum = 0.f, qsum = 0.f;
        #pragma unroll
        for (int j = 0; j < 4; j++) {
            int n = n0 + wn + j * 16 + cn;
            float bv = bias[n];
            #pragma unroll
            for (int i = 0; i < 4; i++) {
                #pragma unroll
                for (int r = 0; r < 4; r++) {
                    int m = m0 + wm + i * 16 + rb + r;
                    long idx = (long)bl * sC + (long)m * N + n;
                    float xn = (FA[idx] - st.x) * st.y;
                    float v = (acc[i][j][r] + bv + xn) * WTp[m * 256 + n] + BTp[m * 256 + n];
                    Cf[idx] = v;
                    ssum += v;
                    qsum += v * v;
                }
            }
        }
        ssum = block_sum256(ssum, sc);
        qsum = block_sum256(qsum, sc);
        if (tid == 0)
            partOut[bl * 16 + blockIdx.x * 2 + blockIdx.y] = make_float2(ssum, qsum);
    } else {
        #pragma unroll
        for (int j = 0; j < 4; j++) {
            int n = n0 + wn + j * 16 + cn;
            float bv = bias ? bias[n] : 0.f;
            #pragma unroll
            for (int i = 0; i < 4; i++) {
                #pragma unroll
                for (int r = 0; r < 4; r++) {
                    int m = m0 + wm + i * 16 + rb + r;
                    float v = acc[i][j][r] + bv;
                    long idx = (long)bl * sC + (long)m * N + n;
                    if (Cf) Cf[idx] = v;
                    if (Cb) Cb[idx] = f2b(v);
                }
            }
        }
    }
}

// ---------------- w1/w2 GEMV ----------------
__global__ __launch_bounds__(256) void k_dots(const ushort* __restrict__ X,
                                              const float* __restrict__ va,
                                              float* __restrict__ o1,
                                              float* __restrict__ o2) {
    int wid = threadIdx.x >> 6, lane = threadIdx.x & 63;
    long row = (long)blockIdx.x * 4 + wid;
    uint2 xv = *(const uint2*)(X + row * 256 + lane * 4);
    float x0 = b2f(xv.x), x1 = b2f(xv.x >> 16), x2 = b2f(xv.y), x3 = b2f(xv.y >> 16);
    float4 v1 = *(const float4*)&va[lane * 4];
    float4 v2 = *(const float4*)&va[256 + lane * 4];
    float s1 = x0 * v1.x + x1 * v1.y + x2 * v1.z + x3 * v1.w;
    float s2 = x0 * v2.x + x1 * v2.y + x2 * v2.z + x3 * v2.w;
    #pragma unroll
    for (int o = 32; o > 0; o >>= 1) { s1 += __shfl_xor(s1, o, 64); s2 += __shfl_xor(s2, o, 64); }
    if (lane == 0) { o1[row] = s1; o2[row] = s2; }
}

// ------- per-bl global max of w2 -------
__global__ __launch_bounds__(256) void k_w2max(const float* __restrict__ w2v,
                                               float* __restrict__ w2m) {
    __shared__ float sc[4];
    int bl = blockIdx.x;
    float4 v = *(const float4*)&w2v[(long)bl * 1024 + threadIdx.x * 4];
    float m = fmaxf(fmaxf(v.x, v.y), fmaxf(v.z, v.w));
    m = block_max256(m, sc);
    if (threadIdx.x == 0) w2m[bl] = m;
}

DI float pcalc(float w1, float w2, float mr, uint bit) {
    float e = w1 + w2;
    e = (e > 0.f) ? e : 0.2f * e;
    float pp = __expf(e - mr);
    return bit ? pp : 0.f;
}

// ------- MFMA attention v6: barrier-free — P computed directly in A-fragment regs ----
// Lane computes p[row=mt*16+(lane&15)][j=ks*32+(lane>>4)*8+t] == A-frag layout.
// FUSE=1: epilogue computes as*elu(out)+bs*gcn+x -> Af fp32 + LN partials.
template<int FUSE>
__global__ __launch_bounds__(256, 3) void k_attn_mf(
    const ushort* __restrict__ WhT,   // [48][256][1024] bf16
    const float* __restrict__ w1v, const float* __restrict__ w2v,
    const float* __restrict__ w2m,    // [48]
    const uint* __restrict__ maskw,   // [1024][32]
    ushort* __restrict__ outB,
    const float* __restrict__ gcn, const float* __restrict__ xf,
    const float* __restrict__ alpha,
    float* __restrict__ outF, float2* __restrict__ part) {
    __shared__ float w2s[1024];
    __shared__ uint msk[64 * 33];        // padded stride 33
    __shared__ float sc[4];
    int d = blockIdx.x;                  // 768 blocks
    int lidx = (d & 7) * 96 + (d >> 3);  // XCD-chunked: 6 bl per XCD
    int bl = lidx >> 4;
    int i0 = (lidx & 15) * 64;
    int tid = threadIdx.x;
    #pragma unroll
    for (int q = 0; q < 4; q++) w2s[tid + q * 256] = w2v[(long)bl * 1024 + tid + q * 256];
    {   // mask staging: 2048 words, coalesced, padded stride
        const uint4* gm = (const uint4*)(maskw + (long)i0 * 32);
        uint4 ma = gm[tid * 2], mb = gm[tid * 2 + 1];
        int r0 = tid >> 2, w0 = (tid & 3) * 8;
        uint* mp = &msk[r0 * 33 + w0];
        mp[0] = ma.x; mp[1] = ma.y; mp[2] = ma.z; mp[3] = ma.w;
        mp[4] = mb.x; mp[5] = mb.y; mp[6] = mb.z; mp[7] = mb.w;
    }
    __syncthreads();
    const int lane = tid & 63, w = tid >> 6;
    const int wn = w * 64;
    const int fr = lane & 15, fg = lane >> 4, fk8 = fg * 8;
    const float w2mv = w2m[bl];
    float w1r[4], mr[4], sloc[4];
    #pragma unroll
    for (int mt = 0; mt < 4; mt++) {
        float wv = w1v[(long)bl * 1024 + i0 + mt * 16 + fr];
        w1r[mt] = wv;
        float e0 = wv + w2mv;
        mr[mt] = (e0 > 0.f) ? e0 : 0.2f * e0;
        sloc[mt] = 0.f;
    }
    f32x4 acc[4][4] = {};
    const ushort* bp = WhT + (long)bl * SLAB;
    bf16x8 bgbuf[2][4];
    #pragma unroll
    for (int nt = 0; nt < 4; nt++)
        bgbuf[0][nt] = *(const bf16x8*)&bp[(long)(wn + nt * 16 + fr) * 1024 + fk8];
    #pragma unroll 2
    for (int ks = 0; ks < 32; ks++) {
        if (ks < 31) {
            int kb = (ks + 1) * 32 + fk8;
            #pragma unroll
            for (int nt = 0; nt < 4; nt++)
                bgbuf[(ks + 1) & 1][nt] =
                    *(const bf16x8*)&bp[(long)(wn + nt * 16 + fr) * 1024 + kb];
        }
        float4 wa = *(const float4*)&w2s[ks * 32 + fk8];
        float4 wb = *(const float4*)&w2s[ks * 32 + fk8 + 4];
        #pragma unroll
        for (int mt = 0; mt < 4; mt++) {
            uint mby = (msk[(mt * 16 + fr) * 33 + ks] >> (fg * 8)) & 0xffu;
            float p0 = pcalc(w1r[mt], wa.x, mr[mt], mby & 1);
            float p1 = pcalc(w1r[mt], wa.y, mr[mt], (mby >> 1) & 1);
            float p2 = pcalc(w1r[mt], wa.z, mr[mt], (mby >> 2) & 1);
            float p3 = pcalc(w1r[mt], wa.w, mr[mt], (mby >> 3) & 1);
            float p4 = pcalc(w1r[mt], wb.x, mr[mt], (mby >> 4) & 1);
            float p5 = pcalc(w1r[mt], wb.y, mr[mt], (mby >> 5) & 1);
            float p6 = pcalc(w1r[mt], wb.z, mr[mt], (mby >> 6) & 1);
            float p7 = pcalc(w1r[mt], wb.w, mr[mt], (mby >> 7) & 1);
            sloc[mt] += p0 + p1 + p2 + p3 + p4 + p5 + p6 + p7;
            bf16x8 af;
            uint* ap = (uint*)&af;
            ap[0] = pack2(p0, p1);
            ap[1] = pack2(p2, p3);
            ap[2] = pack2(p4, p5);
            ap[3] = pack2(p6, p7);
            #pragma unroll
            for (int nt = 0; nt < 4; nt++)
                acc[mt][nt] = __builtin_amdgcn_mfma_f32_16x16x32_bf16(
                    af, bgbuf[ks & 1][nt], acc[mt][nt], 0, 0, 0);
        }
    }
    float inv[4];
    #pragma unroll
    for (int mt = 0; mt < 4; mt++) {
        float s = sloc[mt];
        s += __shfl_xor(s, 16, 64);
        s += __shfl_xor(s, 32, 64);
        inv[mt] = 1.f / s;
    }
    float as = 0.f, bs = 0.f, ssum = 0.f, qsum = 0.f;
    if (FUSE) { as = 1.f / (1.f + __expf(-alpha[0])); bs = 1.f - as; }
    #pragma unroll
    for (int mt = 0; mt < 4; mt++) {
        #pragma unroll
        for (int r = 0; r < 4; r++) {
            float si = __shfl(inv[mt], fg * 4 + r, 64);
            int i = mt * 16 + fg * 4 + r;
            #pragma unroll
            for (int nt = 0; nt < 4; nt++) {
                int c = wn + nt * 16 + fr;
                float v = acc[mt][nt][r] * si;
                v = (v > 0.f) ? v : __expf(v) - 1.f;       // elu
                long idx = (long)bl * SLAB + (long)(i0 + i) * 256 + c;
                if (FUSE) {
                    float fv = as * v + bs * gcn[idx] + xf[idx];
                    outF[idx] = fv;
                    ssum += fv;
                    qsum += fv * fv;
                } else {
                    outB[idx] = f2b(v);
                }
            }
        }
    }
    if (FUSE) {
        ssum = block_sum256(ssum, sc);
        qsum = block_sum256(qsum, sc);
        if (tid == 0) part[bl * 16 + (lidx & 15)] = make_float2(ssum, qsum);
    }
}

// ------- stats from 16 partials per slab -------
__global__ void k_stats16(const float2* __restrict__ part, float2* __restrict__ stats) {
    int bl = blockIdx.x, t = threadIdx.x;
    float s = 0.f, q = 0.f;
    if (t < 16) { float2 v = part[bl * 16 + t]; s = v.x; q = v.y; }
    #pragma unroll
    for (int o = 8; o > 0; o >>= 1) { s += __shfl_xor(s, o, 64); q += __shfl_xor(q, o, 64); }
    if (t == 0) {
        float mean = s / (float)SLAB;
        float var = q / (float)SLAB - mean * mean;
        stats[bl] = make_float2(mean, 1.f / sqrtf(var + 1e-5f));
    }
}

// ------- LN apply, bf16 out only -------
__global__ __launch_bounds__(256) void k_ln_apply(const float4* __restrict__ x,
                                                  const float2* __restrict__ stats,
                                                  ushort* __restrict__ ob) {
    long i = (long)blockIdx.x * 256 + threadIdx.x;
    int bl = (int)(i >> 16);
    float2 st = stats[bl];
    float4 v = x[i];
    uint2 ow;
    ow.x = pack2((v.x - st.x) * st.y, (v.y - st.x) * st.y);
    ow.y = pack2((v.z - st.x) * st.y, (v.w - st.x) * st.y);
    ((uint2*)ob)[i] = ow;
}

// ------- final normalize + transpose back to [b][c][n][l] -------
__global__ __launch_bounds__(256) void k_out(const float* __restrict__ x,
                                             const float2* __restrict__ stats,
                                             float* __restrict__ out) {
    int n = blockIdx.x, b = blockIdx.y, c = threadIdx.x;
    float v[12];
    #pragma unroll
    for (int l = 0; l < 12; l++) {
        float2 st = stats[b * 12 + l];
        float t = x[(long)(b * 12 + l) * SLAB + (long)n * 256 + c];
        v[l] = (t - st.x) * st.y;
    }
    float4* op = (float4*)(out + ((long)(b * 256 + c) * 1024 + n) * 12);
    op[0] = make_float4(v[0], v[1], v[2], v[3]);
    op[1] = make_float4(v[4], v[5], v[6], v[7]);
    op[2] = make_float4(v[8], v[9], v[10], v[11]);
}

// =================================================================
extern "C" void kernel_launch(void* const* d_in, const int* in_sizes, int n_in,
                              void* d_out, int out_size, void* d_ws, size_t ws_size,
                              hipStream_t stream) {
    (void)in_sizes; (void)n_in; (void)out_size; (void)ws_size;
    const float* x_in = (const float*)d_in[0];
    const int*   dg   = (const int*)d_in[1];
    const float* nv1  = (const float*)d_in[2];
    const float* nv2  = (const float*)d_in[3];
    const float* Wmlp = (const float*)d_in[4];
    const float* bmlp = (const float*)d_in[5];
    const float* Wg0  = (const float*)d_in[6];
    const float* ag0  = (const float*)d_in[7];
    const float* Wgo  = (const float*)d_in[8];
    const float* ago  = (const float*)d_in[9];
    const float* Wg1  = (const float*)d_in[10];
    const float* bg1  = (const float*)d_in[11];
    const float* Wg2  = (const float*)d_in[12];
    const float* bg2  = (const float*)d_in[13];
    const float* Wg3  = (const float*)d_in[14];
    const float* bg3  = (const float*)d_in[15];
    const float* alpha = (const float*)d_in[16];
    const float* wgt  = (const float*)d_in[17];
    const float* bia  = (const float*)d_in[18];
    float* out = (float*)d_out;

    // ---- workspace (~208 MB; Af aliases the dead U1+U2 region) ----
    float* XTf = (float*)d_ws;          // fp32 x_in copy
    float* Bf  = XTf + TOT;             // fp32 gcn; later final pre-LN
    ushort* U1 = (ushort*)(Bf + TOT);   // Xb bf16
    ushort* U2 = U1 + TOT;              // XTT; later g (attn1 out)
    float* Af  = (float*)U1;            // fp32 fuse output, live after U1/U2 dead
    ushort* U3 = U2 + TOT;              // x1b; later xn bf16
    ushort* U4 = U3 + TOT;              // WhT; later h bf16
    ushort* ADPB = U4 + TOT;            // [1024][1024]
    ushort* WMLPB = ADPB + (long)1024 * 1024;
    ushort* WG0T = WMLPB + 131072;
    ushort* WGOT = WG0T + 65536;
    ushort* WGIB = WGOT + 65536;        // [512][256] interleaved g1/g2
    ushort* WG3B = WGIB + 131072;
    float* BIASI = (float*)(WG3B + 65536);  // 512
    float* VA = BIASI + 512;                // 1024
    float* W1V = VA + 1024;
    float* W2V = W1V + 49152;
    float* W2M = W2V + 49152;               // 48 (+pad)
    uint* MASKW = (uint*)(W2M + 64);        // 32768
    float2* PART = (float2*)(MASKW + 32768); // [48][16]
    float2* STATS1 = PART + 48 * 16;
    float2* STATS2 = STATS1 + 48;
    float* WT = (float*)(STATS2 + 48);
    float* BT2 = WT + SLAB;

    dim3 blk(256);
    // prep
    k_wt2<<<dim3(4, 4, 2), blk, 0, stream>>>(Wg0, WG0T, Wgo, WGOT);
    k_wconv<<<512, blk, 0, stream>>>(Wmlp, WMLPB);
    k_wconv<<<256, blk, 0, stream>>>(Wg3, WG3B);
    k_wgi<<<512, blk, 0, stream>>>(Wg1, bg1, Wg2, bg2, WGIB, BIASI);
    k_va<<<256, blk, 0, stream>>>(Wg0, ag0, VA);
    k_va<<<256, blk, 0, stream>>>(Wgo, ago, VA + 512);
    k_wtprep<<<1024, blk, 0, stream>>>(wgt, bia, WT, BT2);
    k_adp<<<1024, blk, 0, stream>>>(nv1, nv2, ADPB);
    k_maskpack<<<128, blk, 0, stream>>>(dg, MASKW);
    k_tin<<<dim3(192, 4, 4), blk, 0, stream>>>(x_in, U1, XTf);
    k_xtt<<<dim3(16, 4, 48), blk, 0, stream>>>(U1, U2);
    // x1 = adp @ x  (Bt = XTT) -> U3 bf16
    k_bgemm<1, 0><<<dim3(8, 2, 48), blk, 0, stream>>>(ADPB, 0, nullptr, 0, 1024, 0, 1024,
        U2, SLAB, nullptr, nullptr, U3, SLAB, nullptr,
        nullptr, nullptr, nullptr, nullptr, nullptr);
    // gcn = [x|x1] @ Wmlp(o,c) + b -> Bf fp32
    k_bgemm<2, 0><<<dim3(8, 2, 48), blk, 0, stream>>>(U1, SLAB, U3, SLAB, 256, 256, 512,
        WMLPB, 0, bmlp, Bf, nullptr, SLAB, nullptr,
        nullptr, nullptr, nullptr, nullptr, nullptr);
    // GAT layer 1
    k_dots<<<12288, blk, 0, stream>>>(U1, VA, W1V, W2V);
    k_w2max<<<48, blk, 0, stream>>>(W2V, W2M);
    k_bgemm<1, 0><<<dim3(2, 8, 48), blk, 0, stream>>>(WG0T, 0, nullptr, 0, 256, 0, 256,
        U1, SLAB, nullptr, nullptr, U4, SLAB, nullptr,
        nullptr, nullptr, nullptr, nullptr, nullptr);
    k_attn_mf<0><<<768, blk, 0, stream>>>(U4, W1V, W2V, W2M, MASKW, U2,
                                          nullptr, nullptr, nullptr, nullptr, nullptr);
    // GAT layer 2
    k_dots<<<12288, blk, 0, stream>>>(U2, VA + 512, W1V, W2V);
    k_w2max<<<48, blk, 0, stream>>>(W2V, W2M);
    k_bgemm<1, 0><<<dim3(2, 8, 48), blk, 0, stream>>>(WGOT, 0, nullptr, 0, 256, 0, 256,
        U2, SLAB, nullptr, nullptr, U4, SLAB, nullptr,
        nullptr, nullptr, nullptr, nullptr, nullptr);
    // attn2 fused epilogue: Af = as*gat + bs*gcn + x, + LN1 partials
    k_attn_mf<1><<<768, blk, 0, stream>>>(U4, W1V, W2V, W2M, MASKW, nullptr,
                                          Bf, XTf, alpha, Af, PART);
    k_stats16<<<48, 64, 0, stream>>>(PART, STATS1);
    k_ln_apply<<<12288, blk, 0, stream>>>((const float4*)Af, STATS1, U3);
    // GLU pair GEMM (interleaved) -> U4 h bf16
    k_bgemm<1, 1><<<dim3(8, 4, 48), blk, 0, stream>>>(U3, SLAB, nullptr, 0, 256, 0, 256,
        WGIB, 0, nullptr, nullptr, U4, SLAB, BIASI,
        nullptr, nullptr, nullptr, nullptr, nullptr);
    // glu3 GEMM + finpre + LN2 partials -> Bf, PART
    k_bgemm<1, 2><<<dim3(8, 2, 48), blk, 0, stream>>>(U4, SLAB, nullptr, 0, 256, 0, 256,
        WG3B, 0, bg3, Bf, nullptr, SLAB, nullptr,
        Af, STATS1, WT, BT2, PART);
    k_stats16<<<48, 64, 0, stream>>>(PART, STATS2);
    k_out<<<dim3(1024, 4), blk, 0, stream>>>(Bf, STATS2, out);
}

// Round 10
// 6112.127 us; speedup vs baseline: 1.0005x; 1.0005x over previous
//
#include <hip/hip_runtime.h>
#include <hip/hip_bf16.h>
#include <math.h>

#define DI __device__ __forceinline__
#define AS1 __attribute__((address_space(1)))
#define AS3 __attribute__((address_space(3)))

static constexpr int  B_ = 4, C_ = 256, N_ = 1024, L_ = 12, BL_ = 48;
static constexpr long SLAB = (long)N_ * C_;          // 262144 elems per (b,l)
static constexpr long TOT  = (long)BL_ * SLAB;       // 12,582,912 elems

typedef __attribute__((ext_vector_type(8))) short bf16x8;
typedef __attribute__((ext_vector_type(4))) float f32x4;
typedef __attribute__((ext_vector_type(4))) uint u32x4;

DI float b2f(uint hw) { return __builtin_bit_cast(float, (hw & 0xffffu) << 16); }
DI ushort f2b(float f) {
    uint u = __builtin_bit_cast(uint, f);
    u += 0x7FFFu + ((u >> 16) & 1u);
    return (ushort)(u >> 16);
}
DI uint pack2(float a, float b) {
    __hip_bfloat162 h = __float22bfloat162_rn(make_float2(a, b));
    uint r;
    __builtin_memcpy(&r, &h, 4);
    return r;
}

DI void gload16(const void* g, void* l) {
    __builtin_amdgcn_global_load_lds((AS1 uint*)g, (AS3 uint*)l, 16, 0, 0);
}

// ---------------- block reductions (256 threads, 4 waves) ----------------
DI float block_sum256(float v, float* sc) {
    #pragma unroll
    for (int o = 32; o > 0; o >>= 1) v += __shfl_xor(v, o, 64);
    int wid = threadIdx.x >> 6;
    __syncthreads();
    if ((threadIdx.x & 63) == 0) sc[wid] = v;
    __syncthreads();
    return sc[0] + sc[1] + sc[2] + sc[3];
}
DI float block_max256(float v, float* sc) {
    #pragma unroll
    for (int o = 32; o > 0; o >>= 1) v = fmaxf(v, __shfl_xor(v, o, 64));
    int wid = threadIdx.x >> 6;
    __syncthreads();
    if ((threadIdx.x & 63) == 0) sc[wid] = v;
    __syncthreads();
    return fmaxf(fmaxf(sc[0], sc[1]), fmaxf(sc[2], sc[3]));
}

// ---------------- adp = softmax(relu(nv1@nv2), axis=1), bf16 out ----------------
__global__ __launch_bounds__(256) void k_adp(const float* __restrict__ nv1,
                                             const float* __restrict__ nv2,
                                             ushort* __restrict__ adp) {
    __shared__ float r[6];
    __shared__ float sc[4];
    int row = blockIdx.x, tid = threadIdx.x;
    if (tid < 6) r[tid] = nv1[row * 6 + tid];
    __syncthreads();
    float e[4];
    #pragma unroll
    for (int q = 0; q < 4; q++) {
        int j = tid + q * 256;
        float s = 0.f;
        #pragma unroll
        for (int k = 0; k < 6; k++) s += r[k] * nv2[k * 1024 + j];
        e[q] = s > 0.f ? s : 0.f;
    }
    float m = fmaxf(fmaxf(e[0], e[1]), fmaxf(e[2], e[3]));
    m = block_max256(m, sc);
    float ps = 0.f;
    #pragma unroll
    for (int q = 0; q < 4; q++) { e[q] = __expf(e[q] - m); ps += e[q]; }
    ps = block_sum256(ps, sc);
    float rinv = 1.f / ps;
    #pragma unroll
    for (int q = 0; q < 4; q++) adp[(long)row * 1024 + tid + q * 256] = f2b(e[q] * rinv);
}

// ------- transpose in: x[b][c][n][l] -> Xb[(b*12+l)][n][c] bf16 + fp32 copy -------
__global__ __launch_bounds__(256) void k_tin(const float* __restrict__ x,
                                             ushort* __restrict__ xb,
                                             float* __restrict__ xf) {
    __shared__ float t[64][65];
    int nl0 = blockIdx.x * 64, c0 = blockIdx.y * 64, b = blockIdx.z;
    int lx = threadIdx.x & 63, ly = threadIdx.x >> 6;
    #pragma unroll
    for (int i = 0; i < 16; i++) {
        int c = c0 + ly + i * 4;
        t[ly + i * 4][lx] = x[(long)(b * 256 + c) * 12288 + nl0 + lx];
    }
    __syncthreads();
    #pragma unroll
    for (int i = 0; i < 16; i++) {
        int nl = nl0 + ly + i * 4;
        int n = nl / 12, l = nl % 12;
        long idx = ((long)(b * 12 + l) * 1024 + n) * 256 + c0 + lx;
        float v = t[lx][ly + i * 4];
        xb[idx] = f2b(v);
        xf[idx] = v;
    }
}

// ---------------- per-bl transpose Xb[n][c] -> XTT[c][n] (bf16) ----------------
__global__ __launch_bounds__(256) void k_xtt(const ushort* __restrict__ X,
                                             ushort* __restrict__ XT) {
    __shared__ ushort t[64][68];
    int bl = blockIdx.z;
    int n0 = blockIdx.x * 64, c0 = blockIdx.y * 64;
    int lx = threadIdx.x & 63, ly = threadIdx.x >> 6;
    const ushort* Xp = X + (long)bl * SLAB;
    #pragma unroll
    for (int i = 0; i < 16; i++)
        t[ly + i * 4][lx] = Xp[(long)(n0 + ly + i * 4) * 256 + c0 + lx];
    __syncthreads();
    ushort* Tp = XT + (long)bl * SLAB;
    #pragma unroll
    for (int i = 0; i < 16; i++)
        Tp[(long)(c0 + ly + i * 4) * 1024 + n0 + lx] = t[lx][ly + i * 4];
}

// -------- GAT weight transposes 256x256 fp32 [c][o] -> bf16 [o][c] --------
__global__ __launch_bounds__(256) void k_wt2(const float* __restrict__ S0, ushort* __restrict__ D0,
                                             const float* __restrict__ S1, ushort* __restrict__ D1) {
    __shared__ float t[64][65];
    const float* S = blockIdx.z ? S1 : S0;
    ushort* D = blockIdx.z ? D1 : D0;
    int c0 = blockIdx.x * 64, o0 = blockIdx.y * 64;
    int lx = threadIdx.x & 63, ly = threadIdx.x >> 6;
    #pragma unroll
    for (int i = 0; i < 16; i++)
        t[ly + i * 4][lx] = S[(long)(c0 + ly + i * 4) * 256 + o0 + lx];
    __syncthreads();
    #pragma unroll
    for (int i = 0; i < 16; i++)
        D[(long)(o0 + ly + i * 4) * 256 + c0 + lx] = f2b(t[lx][ly + i * 4]);
}

// ---------------- fp32 -> bf16 straight cast ----------------
__global__ __launch_bounds__(256) void k_wconv(const float* __restrict__ S, ushort* __restrict__ D) {
    long i = (long)blockIdx.x * 256 + threadIdx.x;
    D[i] = f2b(S[i]);
}

// ------- interleaved GLU weights: WGI[p*32+q] = (q<16 ? Wg1 : Wg2) row p*16+q%16 -------
__global__ __launch_bounds__(256) void k_wgi(const float* __restrict__ W1, const float* __restrict__ b1,
                                             const float* __restrict__ W2, const float* __restrict__ b2,
                                             ushort* __restrict__ WGI, float* __restrict__ BI) {
    int n = blockIdx.x, p = n >> 5, q = n & 31;
    const float* src = (q < 16) ? W1 + (long)(p * 16 + q) * 256
                                : W2 + (long)(p * 16 + q - 16) * 256;
    WGI[(long)n * 256 + threadIdx.x] = f2b(src[threadIdx.x]);
    if (threadIdx.x == 0) BI[n] = (q < 16) ? b1[p * 16 + q] : b2[p * 16 + q - 16];
}

// ----- va = W @ a pair -----
__global__ __launch_bounds__(256) void k_va(const float* __restrict__ W, const float* __restrict__ a,
                                            float* __restrict__ va) {
    __shared__ float sc[4];
    int c = blockIdx.x, t = threadIdx.x;
    float w = W[(long)c * 256 + t];
    float s1 = block_sum256(w * a[t], sc);
    float s2 = block_sum256(w * a[256 + t], sc);
    if (t == 0) { va[c] = s1; va[256 + c] = s2; }
}

// ------- weight/bias prep: wt[n][c] = w[c][n]+1, bt[n][c] = b[c][n] -------
__global__ __launch_bounds__(256) void k_wtprep(const float* __restrict__ w,
                                                const float* __restrict__ b,
                                                float* __restrict__ wt,
                                                float* __restrict__ bt) {
    int n = blockIdx.x, c = threadIdx.x;
    wt[(long)n * 256 + c] = w[(long)c * 1024 + n] + 1.f;
    bt[(long)n * 256 + c] = b[(long)c * 1024 + n];
}

// ------- pack mask bits -------
__global__ __launch_bounds__(256) void k_maskpack(const int* __restrict__ dg,
                                                  uint* __restrict__ maskw) {
    int w = blockIdx.x * 256 + threadIdx.x;
    int row = w >> 5, wo = w & 31;
    uint m = 0;
    #pragma unroll
    for (int b = 0; b < 32; b++)
        m |= (dg[(long)row * 1024 + wo * 32 + b] > 0 ? 1u : 0u) << b;
    maskw[w] = m;
}

// ------- bf16 MFMA GEMM, 2-phase pipelined -------
// GLU=0: plain (+bias) -> Cf/Cb. GLU=1: interleaved g1/g2, h=g1*sig(g2) -> Cb.
// GLU=2: finpre fusion: v=(acc+bias + (FA-m1)*r1)*WTp + BTp -> Cf, + LN partials.
template<int NPAIR, int GLU>
__global__ __launch_bounds__(256) void k_bgemm(
    const ushort* __restrict__ A0, long sA0,
    const ushort* __restrict__ A1, long sA1,
    int lda, int K0, int KK,
    const ushort* __restrict__ Bt, long sBt,
    const float* __restrict__ bias,
    float* __restrict__ Cf, ushort* __restrict__ Cb, long sC,
    const float* __restrict__ biasi,
    const float* __restrict__ FA, const float2* __restrict__ ST1,
    const float* __restrict__ WTp, const float* __restrict__ BTp,
    float2* __restrict__ partOut) {
    __shared__ ushort As[2][128 * 32];
    __shared__ ushort Bs[2][128 * 32];
    __shared__ float sc[4];
    const int tid = threadIdx.x;
    const int bl = blockIdx.z;
    const int m0 = blockIdx.x * 128, n0 = blockIdx.y * 128;
    const int N = gridDim.y * 128;
    const int lane = tid & 63, w = tid >> 6;
    const int wm = (w >> 1) * 64, wn = (w & 1) * 64;
    const int sr = tid >> 2, sk = (tid & 3) * 8;
    const int fr = lane & 15, fk = (lane >> 4) * 8;
    f32x4 acc[4][4] = {};
    const ushort* Ab0 = A0 + (long)bl * sA0;
    const ushort* Ab1 = (NPAIR == 2) ? A1 + (long)bl * sA1 : nullptr;
    const ushort* Bb = Bt + (long)bl * sBt;

    auto stage = [&](int buf, int k0) {
        const ushort* Asrc = Ab0; int kl = k0;
        if (NPAIR == 2 && k0 >= K0) { Asrc = Ab1; kl = k0 - K0; }
        gload16(&Asrc[(long)(m0 + sr) * lda + kl + sk],      &As[buf][sr * 32 + sk]);
        gload16(&Asrc[(long)(m0 + sr + 64) * lda + kl + sk], &As[buf][(sr + 64) * 32 + sk]);
        gload16(&Bb[(long)(n0 + sr) * KK + k0 + sk],         &Bs[buf][sr * 32 + sk]);
        gload16(&Bb[(long)(n0 + sr + 64) * KK + k0 + sk],    &Bs[buf][(sr + 64) * 32 + sk]);
    };
    auto compute = [&](int buf) {
        bf16x8 af[4], bg[4];
        #pragma unroll
        for (int i = 0; i < 4; i++) {
            af[i] = *(const bf16x8*)&As[buf][(wm + i * 16 + fr) * 32 + fk];
            bg[i] = *(const bf16x8*)&Bs[buf][(wn + i * 16 + fr) * 32 + fk];
        }
        #pragma unroll
        for (int i = 0; i < 4; i++)
            #pragma unroll
            for (int j = 0; j < 4; j++)
                acc[i][j] = __builtin_amdgcn_mfma_f32_16x16x32_bf16(af[i], bg[j], acc[i][j], 0, 0, 0);
    };

    stage(0, 0);
    __syncthreads();
    int cur = 0;
    for (int k0 = 32; k0 < KK; k0 += 32) {
        stage(cur ^ 1, k0);
        compute(cur);
        __syncthreads();
        cur ^= 1;
    }
    compute(cur);

    const int cn = lane & 15, rb = (lane >> 4) * 4;
    if (GLU == 1) {
        #pragma unroll
        for (int nt = 0; nt < 4; nt += 2) {
            int n1 = n0 + wn + nt * 16 + cn;
            int hcol = ((n1 >> 5) << 4) + cn;
            float b1 = biasi[n1], b2 = biasi[n1 + 16];
            #pragma unroll
            for (int i = 0; i < 4; i++) {
                #pragma unroll
                for (int r = 0; r < 4; r++) {
                    int m = m0 + wm + i * 16 + rb + r;
                    float g1 = acc[i][nt][r] + b1;
                    float g2 = acc[i][nt + 1][r] + b2;
                    float h = g1 / (1.f + __expf(-g2));
                    Cb[(long)bl * sC + (long)m * 256 + hcol] = f2b(h);
                }
            }
        }
    } else if (GLU == 2) {
        float2 st = ST1[bl];
        float ssum = 0.f, qsum = 0.f;
        #pragma unroll
        for (int j = 0; j < 4; j++) {
            int n = n0 + wn + j * 16 + cn;
            float bv = bias[n];
            #pragma unroll
            for (int i = 0; i < 4; i++) {
                #pragma unroll
                for (int r = 0; r < 4; r++) {
                    int m = m0 + wm + i * 16 + rb + r;
                    long idx = (long)bl * sC + (long)m * N + n;
                    float xn = (FA[idx] - st.x) * st.y;
                    float v = (acc[i][j][r] + bv + xn) * WTp[m * 256 + n] + BTp[m * 256 + n];
                    Cf[idx] = v;
                    ssum += v;
                    qsum += v * v;
                }
            }
        }
        ssum = block_sum256(ssum, sc);
        qsum = block_sum256(qsum, sc);
        if (tid == 0)
            partOut[bl * 16 + blockIdx.x * 2 + blockIdx.y] = make_float2(ssum, qsum);
    } else {
        #pragma unroll
        for (int j = 0; j < 4; j++) {
            int n = n0 + wn + j * 16 + cn;
            float bv = bias ? bias[n] : 0.f;
            #pragma unroll
            for (int i = 0; i < 4; i++) {
                #pragma unroll
                for (int r = 0; r < 4; r++) {
                    int m = m0 + wm + i * 16 + rb + r;
                    float v = acc[i][j][r] + bv;
                    long idx = (long)bl * sC + (long)m * N + n;
                    if (Cf) Cf[idx] = v;
                    if (Cb) Cb[idx] = f2b(v);
                }
            }
        }
    }
}

// ---------------- w1/w2 GEMV ----------------
__global__ __launch_bounds__(256) void k_dots(const ushort* __restrict__ X,
                                              const float* __restrict__ va,
                                              float* __restrict__ o1,
                                              float* __restrict__ o2) {
    int wid = threadIdx.x >> 6, lane = threadIdx.x & 63;
    long row = (long)blockIdx.x * 4 + wid;
    uint2 xv = *(const uint2*)(X + row * 256 + lane * 4);
    float x0 = b2f(xv.x), x1 = b2f(xv.x >> 16), x2 = b2f(xv.y), x3 = b2f(xv.y >> 16);
    float4 v1 = *(const float4*)&va[lane * 4];
    float4 v2 = *(const float4*)&va[256 + lane * 4];
    float s1 = x0 * v1.x + x1 * v1.y + x2 * v1.z + x3 * v1.w;
    float s2 = x0 * v2.x + x1 * v2.y + x2 * v2.z + x3 * v2.w;
    #pragma unroll
    for (int o = 32; o > 0; o >>= 1) { s1 += __shfl_xor(s1, o, 64); s2 += __shfl_xor(s2, o, 64); }
    if (lane == 0) { o1[row] = s1; o2[row] = s2; }
}

// ------- per-bl global max of w2 -------
__global__ __launch_bounds__(256) void k_w2max(const float* __restrict__ w2v,
                                               float* __restrict__ w2m) {
    __shared__ float sc[4];
    int bl = blockIdx.x;
    float4 v = *(const float4*)&w2v[(long)bl * 1024 + threadIdx.x * 4];
    float m = fmaxf(fmaxf(v.x, v.y), fmaxf(v.z, v.w));
    m = block_max256(m, sc);
    if (threadIdx.x == 0) w2m[bl] = m;
}

DI float pcalc(float w1, float w2, float mr, uint bit) {
    float e = w1 + w2;
    e = (e > 0.f) ? e : 0.2f * e;
    float pp = __expf(e - mr);
    return bit ? pp : 0.f;
}

// ------- MFMA attention v6b: barrier-free, P built in A-fragment regs (no addr-taking) --
// Lane computes p[row=mt*16+(lane&15)][j=ks*32+(lane>>4)*8+t] == A-frag layout.
// FUSE=1: epilogue computes as*elu(out)+bs*gcn+x -> Af fp32 + LN partials.
template<int FUSE>
__global__ __launch_bounds__(256, 3) void k_attn_mf(
    const ushort* __restrict__ WhT,   // [48][256][1024] bf16
    const float* __restrict__ w1v, const float* __restrict__ w2v,
    const float* __restrict__ w2m,    // [48]
    const uint* __restrict__ maskw,   // [1024][32]
    ushort* __restrict__ outB,
    const float* __restrict__ gcn, const float* __restrict__ xf,
    const float* __restrict__ alpha,
    float* __restrict__ outF, float2* __restrict__ part) {
    __shared__ float w2s[1024];
    __shared__ uint msk[64 * 33];        // padded stride 33
    __shared__ float sc[4];
    int d = blockIdx.x;                  // 768 blocks
    int lidx = (d & 7) * 96 + (d >> 3);  // XCD-chunked: 6 bl per XCD
    int bl = lidx >> 4;
    int i0 = (lidx & 15) * 64;
    int tid = threadIdx.x;
    #pragma unroll
    for (int q = 0; q < 4; q++) w2s[tid + q * 256] = w2v[(long)bl * 1024 + tid + q * 256];
    {   // mask staging: 2048 words, coalesced, padded stride
        const uint4* gm = (const uint4*)(maskw + (long)i0 * 32);
        uint4 ma = gm[tid * 2], mb = gm[tid * 2 + 1];
        int r0 = tid >> 2, w0 = (tid & 3) * 8;
        uint* mp = &msk[r0 * 33 + w0];
        mp[0] = ma.x; mp[1] = ma.y; mp[2] = ma.z; mp[3] = ma.w;
        mp[4] = mb.x; mp[5] = mb.y; mp[6] = mb.z; mp[7] = mb.w;
    }
    __syncthreads();
    const int lane = tid & 63, w = tid >> 6;
    const int wn = w * 64;
    const int fr = lane & 15, fg = lane >> 4, fk8 = fg * 8;
    const float w2mv = w2m[bl];
    float w1r[4], mr[4], sloc[4];
    #pragma unroll
    for (int mt = 0; mt < 4; mt++) {
        float wv = w1v[(long)bl * 1024 + i0 + mt * 16 + fr];
        w1r[mt] = wv;
        float e0 = wv + w2mv;
        mr[mt] = (e0 > 0.f) ? e0 : 0.2f * e0;
        sloc[mt] = 0.f;
    }
    f32x4 acc[4][4] = {};
    const ushort* bp = WhT + (long)bl * SLAB;
    bf16x8 bgbuf[2][4];
    #pragma unroll
    for (int nt = 0; nt < 4; nt++)
        bgbuf[0][nt] = *(const bf16x8*)&bp[(long)(wn + nt * 16 + fr) * 1024 + fk8];
    #pragma unroll 2
    for (int ks = 0; ks < 32; ks++) {
        if (ks < 31) {
            int kb = (ks + 1) * 32 + fk8;
            #pragma unroll
            for (int nt = 0; nt < 4; nt++)
                bgbuf[(ks + 1) & 1][nt] =
                    *(const bf16x8*)&bp[(long)(wn + nt * 16 + fr) * 1024 + kb];
        }
        float4 wa = *(const float4*)&w2s[ks * 32 + fk8];
        float4 wb = *(const float4*)&w2s[ks * 32 + fk8 + 4];
        #pragma unroll
        for (int mt = 0; mt < 4; mt++) {
            uint mby = (msk[(mt * 16 + fr) * 33 + ks] >> (fg * 8)) & 0xffu;
            float p0 = pcalc(w1r[mt], wa.x, mr[mt], mby & 1);
            float p1 = pcalc(w1r[mt], wa.y, mr[mt], (mby >> 1) & 1);
            float p2 = pcalc(w1r[mt], wa.z, mr[mt], (mby >> 2) & 1);
            float p3 = pcalc(w1r[mt], wa.w, mr[mt], (mby >> 3) & 1);
            float p4 = pcalc(w1r[mt], wb.x, mr[mt], (mby >> 4) & 1);
            float p5 = pcalc(w1r[mt], wb.y, mr[mt], (mby >> 5) & 1);
            float p6 = pcalc(w1r[mt], wb.z, mr[mt], (mby >> 6) & 1);
            float p7 = pcalc(w1r[mt], wb.w, mr[mt], (mby >> 7) & 1);
            sloc[mt] += p0 + p1 + p2 + p3 + p4 + p5 + p6 + p7;
            u32x4 av;                       // register-only fragment build (no addr taken)
            av[0] = pack2(p0, p1);
            av[1] = pack2(p2, p3);
            av[2] = pack2(p4, p5);
            av[3] = pack2(p6, p7);
            bf16x8 af = __builtin_bit_cast(bf16x8, av);
            #pragma unroll
            for (int nt = 0; nt < 4; nt++)
                acc[mt][nt] = __builtin_amdgcn_mfma_f32_16x16x32_bf16(
                    af, bgbuf[ks & 1][nt], acc[mt][nt], 0, 0, 0);
        }
    }
    float inv[4];
    #pragma unroll
    for (int mt = 0; mt < 4; mt++) {
        float s = sloc[mt];
        s += __shfl_xor(s, 16, 64);
        s += __shfl_xor(s, 32, 64);
        inv[mt] = 1.f / s;
    }
    float as = 0.f, bs = 0.f, ssum = 0.f, qsum = 0.f;
    if (FUSE) { as = 1.f / (1.f + __expf(-alpha[0])); bs = 1.f - as; }
    #pragma unroll
    for (int mt = 0; mt < 4; mt++) {
        #pragma unroll
        for (int r = 0; r < 4; r++) {
            float si = __shfl(inv[mt], fg * 4 + r, 64);
            int i = mt * 16 + fg * 4 + r;
            #pragma unroll
            for (int nt = 0; nt < 4; nt++) {
                int c = wn + nt * 16 + fr;
                float v = acc[mt][nt][r] * si;
                v = (v > 0.f) ? v : __expf(v) - 1.f;       // elu
                long idx = (long)bl * SLAB + (long)(i0 + i) * 256 + c;
                if (FUSE) {
                    float fv = as * v + bs * gcn[idx] + xf[idx];
                    outF[idx] = fv;
                    ssum += fv;
                    qsum += fv * fv;
                } else {
                    outB[idx] = f2b(v);
                }
            }
        }
    }
    if (FUSE) {
        ssum = block_sum256(ssum, sc);
        qsum = block_sum256(qsum, sc);
        if (tid == 0) part[bl * 16 + (lidx & 15)] = make_float2(ssum, qsum);
    }
}

// ------- stats from 16 partials per slab -------
__global__ void k_stats16(const float2* __restrict__ part, float2* __restrict__ stats) {
    int bl = blockIdx.x, t = threadIdx.x;
    float s = 0.f, q = 0.f;
    if (t < 16) { float2 v = part[bl * 16 + t]; s = v.x; q = v.y; }
    #pragma unroll
    for (int o = 8; o > 0; o >>= 1) { s += __shfl_xor(s, o, 64); q += __shfl_xor(q, o, 64); }
    if (t == 0) {
        float mean = s / (float)SLAB;
        float var = q / (float)SLAB - mean * mean;
        stats[bl] = make_float2(mean, 1.f / sqrtf(var + 1e-5f));
    }
}

// ------- LN apply, bf16 out only -------
__global__ __launch_bounds__(256) void k_ln_apply(const float4* __restrict__ x,
                                                  const float2* __restrict__ stats,
                                                  ushort* __restrict__ ob) {
    long i = (long)blockIdx.x * 256 + threadIdx.x;
    int bl = (int)(i >> 16);
    float2 st = stats[bl];
    float4 v = x[i];
    uint2 ow;
    ow.x = pack2((v.x - st.x) * st.y, (v.y - st.x) * st.y);
    ow.y = pack2((v.z - st.x) * st.y, (v.w - st.x) * st.y);
    ((uint2*)ob)[i] = ow;
}

// ------- final normalize + transpose back to [b][c][n][l] -------
__global__ __launch_bounds__(256) void k_out(const float* __restrict__ x,
                                             const float2* __restrict__ stats,
                                             float* __restrict__ out) {
    int n = blockIdx.x, b = blockIdx.y, c = threadIdx.x;
    float v[12];
    #pragma unroll
    for (int l = 0; l < 12; l++) {
        float2 st = stats[b * 12 + l];
        float t = x[(long)(b * 12 + l) * SLAB + (long)n * 256 + c];
        v[l] = (t - st.x) * st.y;
    }
    float4* op = (float4*)(out + ((long)(b * 256 + c) * 1024 + n) * 12);
    op[0] = make_float4(v[0], v[1], v[2], v[3]);
    op[1] = make_float4(v[4], v[5], v[6], v[7]);
    op[2] = make_float4(v[8], v[9], v[10], v[11]);
}

// =================================================================
extern "C" void kernel_launch(void* const* d_in, const int* in_sizes, int n_in,
                              void* d_out, int out_size, void* d_ws, size_t ws_size,
                              hipStream_t stream) {
    (void)in_sizes; (void)n_in; (void)out_size; (void)ws_size;
    const float* x_in = (const float*)d_in[0];
    const int*   dg   = (const int*)d_in[1];
    const float* nv1  = (const float*)d_in[2];
    const float* nv2  = (const float*)d_in[3];
    const float* Wmlp = (const float*)d_in[4];
    const float* bmlp = (const float*)d_in[5];
    const float* Wg0  = (const float*)d_in[6];
    const float* ag0  = (const float*)d_in[7];
    const float* Wgo  = (const float*)d_in[8];
    const float* ago  = (const float*)d_in[9];
    const float* Wg1  = (const float*)d_in[10];
    const float* bg1  = (const float*)d_in[11];
    const float* Wg2  = (const float*)d_in[12];
    const float* bg2  = (const float*)d_in[13];
    const float* Wg3  = (const float*)d_in[14];
    const float* bg3  = (const float*)d_in[15];
    const float* alpha = (const float*)d_in[16];
    const float* wgt  = (const float*)d_in[17];
    const float* bia  = (const float*)d_in[18];
    float* out = (float*)d_out;

    // ---- workspace (~208 MB; Af aliases the dead U1+U2 region) ----
    float* XTf = (float*)d_ws;          // fp32 x_in copy
    float* Bf  = XTf + TOT;             // fp32 gcn; later final pre-LN
    ushort* U1 = (ushort*)(Bf + TOT);   // Xb bf16
    ushort* U2 = U1 + TOT;              // XTT; later g (attn1 out)
    float* Af  = (float*)U1;            // fp32 fuse output, live after U1/U2 dead
    ushort* U3 = U2 + TOT;              // x1b; later xn bf16
    ushort* U4 = U3 + TOT;              // WhT; later h bf16
    ushort* ADPB = U4 + TOT;            // [1024][1024]
    ushort* WMLPB = ADPB + (long)1024 * 1024;
    ushort* WG0T = WMLPB + 131072;
    ushort* WGOT = WG0T + 65536;
    ushort* WGIB = WGOT + 65536;        // [512][256] interleaved g1/g2
    ushort* WG3B = WGIB + 131072;
    float* BIASI = (float*)(WG3B + 65536);  // 512
    float* VA = BIASI + 512;                // 1024
    float* W1V = VA + 1024;
    float* W2V = W1V + 49152;
    float* W2M = W2V + 49152;               // 48 (+pad)
    uint* MASKW = (uint*)(W2M + 64);        // 32768
    float2* PART = (float2*)(MASKW + 32768); // [48][16]
    float2* STATS1 = PART + 48 * 16;
    float2* STATS2 = STATS1 + 48;
    float* WT = (float*)(STATS2 + 48);
    float* BT2 = WT + SLAB;

    dim3 blk(256);
    // prep
    k_wt2<<<dim3(4, 4, 2), blk, 0, stream>>>(Wg0, WG0T, Wgo, WGOT);
    k_wconv<<<512, blk, 0, stream>>>(Wmlp, WMLPB);
    k_wconv<<<256, blk, 0, stream>>>(Wg3, WG3B);
    k_wgi<<<512, blk, 0, stream>>>(Wg1, bg1, Wg2, bg2, WGIB, BIASI);
    k_va<<<256, blk, 0, stream>>>(Wg0, ag0, VA);
    k_va<<<256, blk, 0, stream>>>(Wgo, ago, VA + 512);
    k_wtprep<<<1024, blk, 0, stream>>>(wgt, bia, WT, BT2);
    k_adp<<<1024, blk, 0, stream>>>(nv1, nv2, ADPB);
    k_maskpack<<<128, blk, 0, stream>>>(dg, MASKW);
    k_tin<<<dim3(192, 4, 4), blk, 0, stream>>>(x_in, U1, XTf);
    k_xtt<<<dim3(16, 4, 48), blk, 0, stream>>>(U1, U2);
    // x1 = adp @ x  (Bt = XTT) -> U3 bf16
    k_bgemm<1, 0><<<dim3(8, 2, 48), blk, 0, stream>>>(ADPB, 0, nullptr, 0, 1024, 0, 1024,
        U2, SLAB, nullptr, nullptr, U3, SLAB, nullptr,
        nullptr, nullptr, nullptr, nullptr, nullptr);
    // gcn = [x|x1] @ Wmlp(o,c) + b -> Bf fp32
    k_bgemm<2, 0><<<dim3(8, 2, 48), blk, 0, stream>>>(U1, SLAB, U3, SLAB, 256, 256, 512,
        WMLPB, 0, bmlp, Bf, nullptr, SLAB, nullptr,
        nullptr, nullptr, nullptr, nullptr, nullptr);
    // GAT layer 1
    k_dots<<<12288, blk, 0, stream>>>(U1, VA, W1V, W2V);
    k_w2max<<<48, blk, 0, stream>>>(W2V, W2M);
    k_bgemm<1, 0><<<dim3(2, 8, 48), blk, 0, stream>>>(WG0T, 0, nullptr, 0, 256, 0, 256,
        U1, SLAB, nullptr, nullptr, U4, SLAB, nullptr,
        nullptr, nullptr, nullptr, nullptr, nullptr);
    k_attn_mf<0><<<768, blk, 0, stream>>>(U4, W1V, W2V, W2M, MASKW, U2,
                                          nullptr, nullptr, nullptr, nullptr, nullptr);
    // GAT layer 2
    k_dots<<<12288, blk, 0, stream>>>(U2, VA + 512, W1V, W2V);
    k_w2max<<<48, blk, 0, stream>>>(W2V, W2M);
    k_bgemm<1, 0><<<dim3(2, 8, 48), blk, 0, stream>>>(WGOT, 0, nullptr, 0, 256, 0, 256,
        U2, SLAB, nullptr, nullptr, U4, SLAB, nullptr,
        nullptr, nullptr, nullptr, nullptr, nullptr);
    // attn2 fused epilogue: Af = as*gat + bs*gcn + x, + LN1 partials
    k_attn_mf<1><<<768, blk, 0, stream>>>(U4, W1V, W2V, W2M, MASKW, nullptr,
                                          Bf, XTf, alpha, Af, PART);
    k_stats16<<<48, 64, 0, stream>>>(PART, STATS1);
    k_ln_apply<<<12288, blk, 0, stream>>>((const float4*)Af, STATS1, U3);
    // GLU pair GEMM (interleaved) -> U4 h bf16
    k_bgemm<1, 1><<<dim3(8, 4, 48), blk, 0, stream>>>(U3, SLAB, nullptr, 0, 256, 0, 256,
        WGIB, 0, nullptr, nullptr, U4, SLAB, BIASI,
        nullptr, nullptr, nullptr, nullptr, nullptr);
    // glu3 GEMM + finpre + LN2 partials -> Bf, PART
    k_bgemm<1, 2><<<dim3(8, 2, 48), blk, 0, stream>>>(U4, SLAB, nullptr, 0, 256, 0, 256,
        WG3B, 0, bg3, Bf, nullptr, SLAB, nullptr,
        Af, STATS1, WT, BT2, PART);
    k_stats16<<<48, 64, 0, stream>>>(PART, STATS2);
    k_out<<<dim3(1024, 4), blk, 0, stream>>>(Bf, STATS2, out);
}

// Round 11
// 544.606 us; speedup vs baseline: 11.2282x; 11.2230x over previous
//
#include <hip/hip_runtime.h>
#include <hip/hip_bf16.h>
#include <math.h>

#define DI __device__ __forceinline__
#define AS1 __attribute__((address_space(1)))
#define AS3 __attribute__((address_space(3)))

static constexpr int  B_ = 4, C_ = 256, N_ = 1024, L_ = 12, BL_ = 48;
static constexpr long SLAB = (long)N_ * C_;          // 262144 elems per (b,l)
static constexpr long TOT  = (long)BL_ * SLAB;       // 12,582,912 elems

typedef __attribute__((ext_vector_type(8))) short bf16x8;
typedef __attribute__((ext_vector_type(4))) float f32x4;
typedef __attribute__((ext_vector_type(4))) uint u32x4;

DI float b2f(uint hw) { return __builtin_bit_cast(float, (hw & 0xffffu) << 16); }
DI ushort f2b(float f) {
    uint u = __builtin_bit_cast(uint, f);
    u += 0x7FFFu + ((u >> 16) & 1u);
    return (ushort)(u >> 16);
}
DI uint pack2(float a, float b) {
    __hip_bfloat162 h = __float22bfloat162_rn(make_float2(a, b));
    uint r;
    __builtin_memcpy(&r, &h, 4);
    return r;
}

DI void gload16(const void* g, void* l) {
    __builtin_amdgcn_global_load_lds((AS1 uint*)g, (AS3 uint*)l, 16, 0, 0);
}

// ---------------- block reductions (256 threads, 4 waves) ----------------
DI float block_sum256(float v, float* sc) {
    #pragma unroll
    for (int o = 32; o > 0; o >>= 1) v += __shfl_xor(v, o, 64);
    int wid = threadIdx.x >> 6;
    __syncthreads();
    if ((threadIdx.x & 63) == 0) sc[wid] = v;
    __syncthreads();
    return sc[0] + sc[1] + sc[2] + sc[3];
}
DI float block_max256(float v, float* sc) {
    #pragma unroll
    for (int o = 32; o > 0; o >>= 1) v = fmaxf(v, __shfl_xor(v, o, 64));
    int wid = threadIdx.x >> 6;
    __syncthreads();
    if ((threadIdx.x & 63) == 0) sc[wid] = v;
    __syncthreads();
    return fmaxf(fmaxf(sc[0], sc[1]), fmaxf(sc[2], sc[3]));
}

// ---------------- adp = softmax(relu(nv1@nv2), axis=1), bf16 out ----------------
__global__ __launch_bounds__(256) void k_adp(const float* __restrict__ nv1,
                                             const float* __restrict__ nv2,
                                             ushort* __restrict__ adp) {
    __shared__ float r[6];
    __shared__ float sc[4];
    int row = blockIdx.x, tid = threadIdx.x;
    if (tid < 6) r[tid] = nv1[row * 6 + tid];
    __syncthreads();
    float e[4];
    #pragma unroll
    for (int q = 0; q < 4; q++) {
        int j = tid + q * 256;
        float s = 0.f;
        #pragma unroll
        for (int k = 0; k < 6; k++) s += r[k] * nv2[k * 1024 + j];
        e[q] = s > 0.f ? s : 0.f;
    }
    float m = fmaxf(fmaxf(e[0], e[1]), fmaxf(e[2], e[3]));
    m = block_max256(m, sc);
    float ps = 0.f;
    #pragma unroll
    for (int q = 0; q < 4; q++) { e[q] = __expf(e[q] - m); ps += e[q]; }
    ps = block_sum256(ps, sc);
    float rinv = 1.f / ps;
    #pragma unroll
    for (int q = 0; q < 4; q++) adp[(long)row * 1024 + tid + q * 256] = f2b(e[q] * rinv);
}

// ------- transpose in: x[b][c][n][l] -> Xb[(b*12+l)][n][c] bf16 + fp32 copy -------
__global__ __launch_bounds__(256) void k_tin(const float* __restrict__ x,
                                             ushort* __restrict__ xb,
                                             float* __restrict__ xf) {
    __shared__ float t[64][65];
    int nl0 = blockIdx.x * 64, c0 = blockIdx.y * 64, b = blockIdx.z;
    int lx = threadIdx.x & 63, ly = threadIdx.x >> 6;
    #pragma unroll
    for (int i = 0; i < 16; i++) {
        int c = c0 + ly + i * 4;
        t[ly + i * 4][lx] = x[(long)(b * 256 + c) * 12288 + nl0 + lx];
    }
    __syncthreads();
    #pragma unroll
    for (int i = 0; i < 16; i++) {
        int nl = nl0 + ly + i * 4;
        int n = nl / 12, l = nl % 12;
        long idx = ((long)(b * 12 + l) * 1024 + n) * 256 + c0 + lx;
        float v = t[lx][ly + i * 4];
        xb[idx] = f2b(v);
        xf[idx] = v;
    }
}

// ---------------- per-bl transpose Xb[n][c] -> XTT[c][n] (bf16) ----------------
__global__ __launch_bounds__(256) void k_xtt(const ushort* __restrict__ X,
                                             ushort* __restrict__ XT) {
    __shared__ ushort t[64][68];
    int bl = blockIdx.z;
    int n0 = blockIdx.x * 64, c0 = blockIdx.y * 64;
    int lx = threadIdx.x & 63, ly = threadIdx.x >> 6;
    const ushort* Xp = X + (long)bl * SLAB;
    #pragma unroll
    for (int i = 0; i < 16; i++)
        t[ly + i * 4][lx] = Xp[(long)(n0 + ly + i * 4) * 256 + c0 + lx];
    __syncthreads();
    ushort* Tp = XT + (long)bl * SLAB;
    #pragma unroll
    for (int i = 0; i < 16; i++)
        Tp[(long)(c0 + ly + i * 4) * 1024 + n0 + lx] = t[lx][ly + i * 4];
}

// -------- GAT weight transposes 256x256 fp32 [c][o] -> bf16 [o][c] --------
__global__ __launch_bounds__(256) void k_wt2(const float* __restrict__ S0, ushort* __restrict__ D0,
                                             const float* __restrict__ S1, ushort* __restrict__ D1) {
    __shared__ float t[64][65];
    const float* S = blockIdx.z ? S1 : S0;
    ushort* D = blockIdx.z ? D1 : D0;
    int c0 = blockIdx.x * 64, o0 = blockIdx.y * 64;
    int lx = threadIdx.x & 63, ly = threadIdx.x >> 6;
    #pragma unroll
    for (int i = 0; i < 16; i++)
        t[ly + i * 4][lx] = S[(long)(c0 + ly + i * 4) * 256 + o0 + lx];
    __syncthreads();
    #pragma unroll
    for (int i = 0; i < 16; i++)
        D[(long)(o0 + ly + i * 4) * 256 + c0 + lx] = f2b(t[lx][ly + i * 4]);
}

// ---------------- fp32 -> bf16 straight cast ----------------
__global__ __launch_bounds__(256) void k_wconv(const float* __restrict__ S, ushort* __restrict__ D) {
    long i = (long)blockIdx.x * 256 + threadIdx.x;
    D[i] = f2b(S[i]);
}

// ------- interleaved GLU weights: WGI[p*32+q] = (q<16 ? Wg1 : Wg2) row p*16+q%16 -------
__global__ __launch_bounds__(256) void k_wgi(const float* __restrict__ W1, const float* __restrict__ b1,
                                             const float* __restrict__ W2, const float* __restrict__ b2,
                                             ushort* __restrict__ WGI, float* __restrict__ BI) {
    int n = blockIdx.x, p = n >> 5, q = n & 31;
    const float* src = (q < 16) ? W1 + (long)(p * 16 + q) * 256
                                : W2 + (long)(p * 16 + q - 16) * 256;
    WGI[(long)n * 256 + threadIdx.x] = f2b(src[threadIdx.x]);
    if (threadIdx.x == 0) BI[n] = (q < 16) ? b1[p * 16 + q] : b2[p * 16 + q - 16];
}

// ----- va = W @ a pair -----
__global__ __launch_bounds__(256) void k_va(const float* __restrict__ W, const float* __restrict__ a,
                                            float* __restrict__ va) {
    __shared__ float sc[4];
    int c = blockIdx.x, t = threadIdx.x;
    float w = W[(long)c * 256 + t];
    float s1 = block_sum256(w * a[t], sc);
    float s2 = block_sum256(w * a[256 + t], sc);
    if (t == 0) { va[c] = s1; va[256 + c] = s2; }
}

// ------- weight/bias prep: wt[n][c] = w[c][n]+1, bt[n][c] = b[c][n] -------
__global__ __launch_bounds__(256) void k_wtprep(const float* __restrict__ w,
                                                const float* __restrict__ b,
                                                float* __restrict__ wt,
                                                float* __restrict__ bt) {
    int n = blockIdx.x, c = threadIdx.x;
    wt[(long)n * 256 + c] = w[(long)c * 1024 + n] + 1.f;
    bt[(long)n * 256 + c] = b[(long)c * 1024 + n];
}

// ------- pack mask bits -------
__global__ __launch_bounds__(256) void k_maskpack(const int* __restrict__ dg,
                                                  uint* __restrict__ maskw) {
    int w = blockIdx.x * 256 + threadIdx.x;
    int row = w >> 5, wo = w & 31;
    uint m = 0;
    #pragma unroll
    for (int b = 0; b < 32; b++)
        m |= (dg[(long)row * 1024 + wo * 32 + b] > 0 ? 1u : 0u) << b;
    maskw[w] = m;
}

// ------- bf16 MFMA GEMM, 2-phase pipelined -------
// GLU=0: plain (+bias) -> Cf/Cb. GLU=1: interleaved g1/g2, h=g1*sig(g2) -> Cb.
// GLU=2: finpre fusion: v=(acc+bias + (FA-m1)*r1)*WTp + BTp -> Cf, + LN partials.
template<int NPAIR, int GLU>
__global__ __launch_bounds__(256) void k_bgemm(
    const ushort* __restrict__ A0, long sA0,
    const ushort* __restrict__ A1, long sA1,
    int lda, int K0, int KK,
    const ushort* __restrict__ Bt, long sBt,
    const float* __restrict__ bias,
    float* __restrict__ Cf, ushort* __restrict__ Cb, long sC,
    const float* __restrict__ biasi,
    const float* __restrict__ FA, const float2* __restrict__ ST1,
    const float* __restrict__ WTp, const float* __restrict__ BTp,
    float2* __restrict__ partOut) {
    __shared__ ushort As[2][128 * 32];
    __shared__ ushort Bs[2][128 * 32];
    __shared__ float sc[4];
    const int tid = threadIdx.x;
    const int bl = blockIdx.z;
    const int m0 = blockIdx.x * 128, n0 = blockIdx.y * 128;
    const int N = gridDim.y * 128;
    const int lane = tid & 63, w = tid >> 6;
    const int wm = (w >> 1) * 64, wn = (w & 1) * 64;
    const int sr = tid >> 2, sk = (tid & 3) * 8;
    const int fr = lane & 15, fk = (lane >> 4) * 8;
    f32x4 acc[4][4] = {};
    const ushort* Ab0 = A0 + (long)bl * sA0;
    const ushort* Ab1 = (NPAIR == 2) ? A1 + (long)bl * sA1 : nullptr;
    const ushort* Bb = Bt + (long)bl * sBt;

    auto stage = [&](int buf, int k0) {
        const ushort* Asrc = Ab0; int kl = k0;
        if (NPAIR == 2 && k0 >= K0) { Asrc = Ab1; kl = k0 - K0; }
        gload16(&Asrc[(long)(m0 + sr) * lda + kl + sk],      &As[buf][sr * 32 + sk]);
        gload16(&Asrc[(long)(m0 + sr + 64) * lda + kl + sk], &As[buf][(sr + 64) * 32 + sk]);
        gload16(&Bb[(long)(n0 + sr) * KK + k0 + sk],         &Bs[buf][sr * 32 + sk]);
        gload16(&Bb[(long)(n0 + sr + 64) * KK + k0 + sk],    &Bs[buf][(sr + 64) * 32 + sk]);
    };
    auto compute = [&](int buf) {
        bf16x8 af[4], bg[4];
        #pragma unroll
        for (int i = 0; i < 4; i++) {
            af[i] = *(const bf16x8*)&As[buf][(wm + i * 16 + fr) * 32 + fk];
            bg[i] = *(const bf16x8*)&Bs[buf][(wn + i * 16 + fr) * 32 + fk];
        }
        #pragma unroll
        for (int i = 0; i < 4; i++)
            #pragma unroll
            for (int j = 0; j < 4; j++)
                acc[i][j] = __builtin_amdgcn_mfma_f32_16x16x32_bf16(af[i], bg[j], acc[i][j], 0, 0, 0);
    };

    stage(0, 0);
    __syncthreads();
    int cur = 0;
    for (int k0 = 32; k0 < KK; k0 += 32) {
        stage(cur ^ 1, k0);
        compute(cur);
        __syncthreads();
        cur ^= 1;
    }
    compute(cur);

    const int cn = lane & 15, rb = (lane >> 4) * 4;
    if (GLU == 1) {
        #pragma unroll
        for (int nt = 0; nt < 4; nt += 2) {
            int n1 = n0 + wn + nt * 16 + cn;
            int hcol = ((n1 >> 5) << 4) + cn;
            float b1 = biasi[n1], b2 = biasi[n1 + 16];
            #pragma unroll
            for (int i = 0; i < 4; i++) {
                #pragma unroll
                for (int r = 0; r < 4; r++) {
                    int m = m0 + wm + i * 16 + rb + r;
                    float g1 = acc[i][nt][r] + b1;
                    float g2 = acc[i][nt + 1][r] + b2;
                    float h = g1 / (1.f + __expf(-g2));
                    Cb[(long)bl * sC + (long)m * 256 + hcol] = f2b(h);
                }
            }
        }
    } else if (GLU == 2) {
        float2 st = ST1[bl];
        float ssum = 0.f, qsum = 0.f;
        #pragma unroll
        for (int j = 0; j < 4; j++) {
            int n = n0 + wn + j * 16 + cn;
            float bv = bias[n];
            #pragma unroll
            for (int i = 0; i < 4; i++) {
                #pragma unroll
                for (int r = 0; r < 4; r++) {
                    int m = m0 + wm + i * 16 + rb + r;
                    long idx = (long)bl * sC + (long)m * N + n;
                    float xn = (FA[idx] - st.x) * st.y;
                    float v = (acc[i][j][r] + bv + xn) * WTp[m * 256 + n] + BTp[m * 256 + n];
                    Cf[idx] = v;
                    ssum += v;
                    qsum += v * v;
                }
            }
        }
        ssum = block_sum256(ssum, sc);
        qsum = block_sum256(qsum, sc);
        if (tid == 0)
            partOut[bl * 16 + blockIdx.x * 2 + blockIdx.y] = make_float2(ssum, qsum);
    } else {
        #pragma unroll
        for (int j = 0; j < 4; j++) {
            int n = n0 + wn + j * 16 + cn;
            float bv = bias ? bias[n] : 0.f;
            #pragma unroll
            for (int i = 0; i < 4; i++) {
                #pragma unroll
                for (int r = 0; r < 4; r++) {
                    int m = m0 + wm + i * 16 + rb + r;
                    float v = acc[i][j][r] + bv;
                    long idx = (long)bl * sC + (long)m * N + n;
                    if (Cf) Cf[idx] = v;
                    if (Cb) Cb[idx] = f2b(v);
                }
            }
        }
    }
}

// ---------------- w1/w2 GEMV ----------------
__global__ __launch_bounds__(256) void k_dots(const ushort* __restrict__ X,
                                              const float* __restrict__ va,
                                              float* __restrict__ o1,
                                              float* __restrict__ o2) {
    int wid = threadIdx.x >> 6, lane = threadIdx.x & 63;
    long row = (long)blockIdx.x * 4 + wid;
    uint2 xv = *(const uint2*)(X + row * 256 + lane * 4);
    float x0 = b2f(xv.x), x1 = b2f(xv.x >> 16), x2 = b2f(xv.y), x3 = b2f(xv.y >> 16);
    float4 v1 = *(const float4*)&va[lane * 4];
    float4 v2 = *(const float4*)&va[256 + lane * 4];
    float s1 = x0 * v1.x + x1 * v1.y + x2 * v1.z + x3 * v1.w;
    float s2 = x0 * v2.x + x1 * v2.y + x2 * v2.z + x3 * v2.w;
    #pragma unroll
    for (int o = 32; o > 0; o >>= 1) { s1 += __shfl_xor(s1, o, 64); s2 += __shfl_xor(s2, o, 64); }
    if (lane == 0) { o1[row] = s1; o2[row] = s2; }
}

// ------- per-bl global max of w2 -------
__global__ __launch_bounds__(256) void k_w2max(const float* __restrict__ w2v,
                                               float* __restrict__ w2m) {
    __shared__ float sc[4];
    int bl = blockIdx.x;
    float4 v = *(const float4*)&w2v[(long)bl * 1024 + threadIdx.x * 4];
    float m = fmaxf(fmaxf(v.x, v.y), fmaxf(v.z, v.w));
    m = block_max256(m, sc);
    if (threadIdx.x == 0) w2m[bl] = m;
}

DI float pcalc(float w1, float w2, float mr, uint bit) {
    float e = w1 + w2;
    e = (e > 0.f) ? e : 0.2f * e;
    float pp = __expf(e - mr);
    return bit ? pp : 0.f;
}

// One P+MFMA step at k-slot KS using the NAMED register array BG (rule #20:
// every register access compile-time-constant — no runtime-indexed reg arrays).
#define PSTEP(KS, BG)                                                          \
    do {                                                                       \
        const int ks_ = (KS);                                                  \
        float4 wa = *(const float4*)&w2s[ks_ * 32 + fk8];                      \
        float4 wb = *(const float4*)&w2s[ks_ * 32 + fk8 + 4];                  \
        _Pragma("unroll")                                                      \
        for (int mt = 0; mt < 4; mt++) {                                       \
            uint mby = (msk[(mt * 16 + fr) * 33 + ks_] >> (fg * 8)) & 0xffu;   \
            float p0 = pcalc(w1r[mt], wa.x, mr[mt], mby & 1);                  \
            float p1 = pcalc(w1r[mt], wa.y, mr[mt], (mby >> 1) & 1);           \
            float p2 = pcalc(w1r[mt], wa.z, mr[mt], (mby >> 2) & 1);           \
            float p3 = pcalc(w1r[mt], wa.w, mr[mt], (mby >> 3) & 1);           \
            float p4 = pcalc(w1r[mt], wb.x, mr[mt], (mby >> 4) & 1);           \
            float p5 = pcalc(w1r[mt], wb.y, mr[mt], (mby >> 5) & 1);           \
            float p6 = pcalc(w1r[mt], wb.z, mr[mt], (mby >> 6) & 1);           \
            float p7 = pcalc(w1r[mt], wb.w, mr[mt], (mby >> 7) & 1);           \
            sloc[mt] += p0 + p1 + p2 + p3 + p4 + p5 + p6 + p7;                 \
            u32x4 av;                                                          \
            av[0] = pack2(p0, p1);                                             \
            av[1] = pack2(p2, p3);                                             \
            av[2] = pack2(p4, p5);                                             \
            av[3] = pack2(p6, p7);                                             \
            bf16x8 af = __builtin_bit_cast(bf16x8, av);                        \
            _Pragma("unroll")                                                  \
            for (int nt = 0; nt < 4; nt++)                                     \
                acc[mt][nt] = __builtin_amdgcn_mfma_f32_16x16x32_bf16(         \
                    af, BG[nt], acc[mt][nt], 0, 0, 0);                         \
        }                                                                      \
    } while (0)

// ------- MFMA attention v6c: barrier-free, P in A-frag regs, NAMED bg dbuf -------
// Lane computes p[row=mt*16+(lane&15)][j=ks*32+(lane>>4)*8+t] == A-frag layout.
// FUSE=1: epilogue computes as*elu(out)+bs*gcn+x -> Af fp32 + LN partials.
template<int FUSE>
__global__ __launch_bounds__(256, 3) void k_attn_mf(
    const ushort* __restrict__ WhT,   // [48][256][1024] bf16
    const float* __restrict__ w1v, const float* __restrict__ w2v,
    const float* __restrict__ w2m,    // [48]
    const uint* __restrict__ maskw,   // [1024][32]
    ushort* __restrict__ outB,
    const float* __restrict__ gcn, const float* __restrict__ xf,
    const float* __restrict__ alpha,
    float* __restrict__ outF, float2* __restrict__ part) {
    __shared__ float w2s[1024];
    __shared__ uint msk[64 * 33];        // padded stride 33
    __shared__ float sc[4];
    int d = blockIdx.x;                  // 768 blocks
    int lidx = (d & 7) * 96 + (d >> 3);  // XCD-chunked: 6 bl per XCD
    int bl = lidx >> 4;
    int i0 = (lidx & 15) * 64;
    int tid = threadIdx.x;
    #pragma unroll
    for (int q = 0; q < 4; q++) w2s[tid + q * 256] = w2v[(long)bl * 1024 + tid + q * 256];
    {   // mask staging: 2048 words, coalesced, padded stride
        const uint4* gm = (const uint4*)(maskw + (long)i0 * 32);
        uint4 ma = gm[tid * 2], mb = gm[tid * 2 + 1];
        int r0 = tid >> 2, w0 = (tid & 3) * 8;
        uint* mp = &msk[r0 * 33 + w0];
        mp[0] = ma.x; mp[1] = ma.y; mp[2] = ma.z; mp[3] = ma.w;
        mp[4] = mb.x; mp[5] = mb.y; mp[6] = mb.z; mp[7] = mb.w;
    }
    __syncthreads();
    const int lane = tid & 63, w = tid >> 6;
    const int wn = w * 64;
    const int fr = lane & 15, fg = lane >> 4, fk8 = fg * 8;
    const float w2mv = w2m[bl];
    float w1r[4], mr[4], sloc[4];
    #pragma unroll
    for (int mt = 0; mt < 4; mt++) {
        float wv = w1v[(long)bl * 1024 + i0 + mt * 16 + fr];
        w1r[mt] = wv;
        float e0 = wv + w2mv;
        mr[mt] = (e0 > 0.f) ? e0 : 0.2f * e0;
        sloc[mt] = 0.f;
    }
    f32x4 acc[4][4] = {};
    const ushort* bp = WhT + (long)bl * SLAB;
    bf16x8 bgA[4], bgB[4];
    #pragma unroll
    for (int nt = 0; nt < 4; nt++)
        bgA[nt] = *(const bf16x8*)&bp[(long)(wn + nt * 16 + fr) * 1024 + fk8];
    #pragma unroll 1
    for (int ks2 = 0; ks2 < 32; ks2 += 2) {
        {   // prefetch ks2+1 -> bgB
            int kb = (ks2 + 1) * 32 + fk8;
            #pragma unroll
            for (int nt = 0; nt < 4; nt++)
                bgB[nt] = *(const bf16x8*)&bp[(long)(wn + nt * 16 + fr) * 1024 + kb];
        }
        PSTEP(ks2, bgA);
        if (ks2 + 2 < 32) {   // prefetch ks2+2 -> bgA
            int kb = (ks2 + 2) * 32 + fk8;
            #pragma unroll
            for (int nt = 0; nt < 4; nt++)
                bgA[nt] = *(const bf16x8*)&bp[(long)(wn + nt * 16 + fr) * 1024 + kb];
        }
        PSTEP(ks2 + 1, bgB);
    }
    float inv[4];
    #pragma unroll
    for (int mt = 0; mt < 4; mt++) {
        float s = sloc[mt];
        s += __shfl_xor(s, 16, 64);
        s += __shfl_xor(s, 32, 64);
        inv[mt] = 1.f / s;
    }
    float as = 0.f, bs = 0.f, ssum = 0.f, qsum = 0.f;
    if (FUSE) { as = 1.f / (1.f + __expf(-alpha[0])); bs = 1.f - as; }
    #pragma unroll
    for (int mt = 0; mt < 4; mt++) {
        #pragma unroll
        for (int r = 0; r < 4; r++) {
            float si = __shfl(inv[mt], fg * 4 + r, 64);
            int i = mt * 16 + fg * 4 + r;
            #pragma unroll
            for (int nt = 0; nt < 4; nt++) {
                int c = wn + nt * 16 + fr;
                float v = acc[mt][nt][r] * si;
                v = (v > 0.f) ? v : __expf(v) - 1.f;       // elu
                long idx = (long)bl * SLAB + (long)(i0 + i) * 256 + c;
                if (FUSE) {
                    float fv = as * v + bs * gcn[idx] + xf[idx];
                    outF[idx] = fv;
                    ssum += fv;
                    qsum += fv * fv;
                } else {
                    outB[idx] = f2b(v);
                }
            }
        }
    }
    if (FUSE) {
        ssum = block_sum256(ssum, sc);
        qsum = block_sum256(qsum, sc);
        if (tid == 0) part[bl * 16 + (lidx & 15)] = make_float2(ssum, qsum);
    }
}

// ------- stats from 16 partials per slab -------
__global__ void k_stats16(const float2* __restrict__ part, float2* __restrict__ stats) {
    int bl = blockIdx.x, t = threadIdx.x;
    float s = 0.f, q = 0.f;
    if (t < 16) { float2 v = part[bl * 16 + t]; s = v.x; q = v.y; }
    #pragma unroll
    for (int o = 8; o > 0; o >>= 1) { s += __shfl_xor(s, o, 64); q += __shfl_xor(q, o, 64); }
    if (t == 0) {
        float mean = s / (float)SLAB;
        float var = q / (float)SLAB - mean * mean;
        stats[bl] = make_float2(mean, 1.f / sqrtf(var + 1e-5f));
    }
}

// ------- LN apply, bf16 out only -------
__global__ __launch_bounds__(256) void k_ln_apply(const float4* __restrict__ x,
                                                  const float2* __restrict__ stats,
                                                  ushort* __restrict__ ob) {
    long i = (long)blockIdx.x * 256 + threadIdx.x;
    int bl = (int)(i >> 16);
    float2 st = stats[bl];
    float4 v = x[i];
    uint2 ow;
    ow.x = pack2((v.x - st.x) * st.y, (v.y - st.x) * st.y);
    ow.y = pack2((v.z - st.x) * st.y, (v.w - st.x) * st.y);
    ((uint2*)ob)[i] = ow;
}

// ------- final normalize + transpose back to [b][c][n][l] -------
__global__ __launch_bounds__(256) void k_out(const float* __restrict__ x,
                                             const float2* __restrict__ stats,
                                             float* __restrict__ out) {
    int n = blockIdx.x, b = blockIdx.y, c = threadIdx.x;
    float v[12];
    #pragma unroll
    for (int l = 0; l < 12; l++) {
        float2 st = stats[b * 12 + l];
        float t = x[(long)(b * 12 + l) * SLAB + (long)n * 256 + c];
        v[l] = (t - st.x) * st.y;
    }
    float4* op = (float4*)(out + ((long)(b * 256 + c) * 1024 + n) * 12);
    op[0] = make_float4(v[0], v[1], v[2], v[3]);
    op[1] = make_float4(v[4], v[5], v[6], v[7]);
    op[2] = make_float4(v[8], v[9], v[10], v[11]);
}

// =================================================================
extern "C" void kernel_launch(void* const* d_in, const int* in_sizes, int n_in,
                              void* d_out, int out_size, void* d_ws, size_t ws_size,
                              hipStream_t stream) {
    (void)in_sizes; (void)n_in; (void)out_size; (void)ws_size;
    const float* x_in = (const float*)d_in[0];
    const int*   dg   = (const int*)d_in[1];
    const float* nv1  = (const float*)d_in[2];
    const float* nv2  = (const float*)d_in[3];
    const float* Wmlp = (const float*)d_in[4];
    const float* bmlp = (const float*)d_in[5];
    const float* Wg0  = (const float*)d_in[6];
    const float* ag0  = (const float*)d_in[7];
    const float* Wgo  = (const float*)d_in[8];
    const float* ago  = (const float*)d_in[9];
    const float* Wg1  = (const float*)d_in[10];
    const float* bg1  = (const float*)d_in[11];
    const float* Wg2  = (const float*)d_in[12];
    const float* bg2  = (const float*)d_in[13];
    const float* Wg3  = (const float*)d_in[14];
    const float* bg3  = (const float*)d_in[15];
    const float* alpha = (const float*)d_in[16];
    const float* wgt  = (const float*)d_in[17];
    const float* bia  = (const float*)d_in[18];
    float* out = (float*)d_out;

    // ---- workspace (~208 MB; Af aliases the dead U1+U2 region) ----
    float* XTf = (float*)d_ws;          // fp32 x_in copy
    float* Bf  = XTf + TOT;             // fp32 gcn; later final pre-LN
    ushort* U1 = (ushort*)(Bf + TOT);   // Xb bf16
    ushort* U2 = U1 + TOT;              // XTT; later g (attn1 out)
    float* Af  = (float*)U1;            // fp32 fuse output, live after U1/U2 dead
    ushort* U3 = U2 + TOT;              // x1b; later xn bf16
    ushort* U4 = U3 + TOT;              // WhT; later h bf16
    ushort* ADPB = U4 + TOT;            // [1024][1024]
    ushort* WMLPB = ADPB + (long)1024 * 1024;
    ushort* WG0T = WMLPB + 131072;
    ushort* WGOT = WG0T + 65536;
    ushort* WGIB = WGOT + 65536;        // [512][256] interleaved g1/g2
    ushort* WG3B = WGIB + 131072;
    float* BIASI = (float*)(WG3B + 65536);  // 512
    float* VA = BIASI + 512;                // 1024
    float* W1V = VA + 1024;
    float* W2V = W1V + 49152;
    float* W2M = W2V + 49152;               // 48 (+pad)
    uint* MASKW = (uint*)(W2M + 64);        // 32768
    float2* PART = (float2*)(MASKW + 32768); // [48][16]
    float2* STATS1 = PART + 48 * 16;
    float2* STATS2 = STATS1 + 48;
    float* WT = (float*)(STATS2 + 48);
    float* BT2 = WT + SLAB;

    dim3 blk(256);
    // prep
    k_wt2<<<dim3(4, 4, 2), blk, 0, stream>>>(Wg0, WG0T, Wgo, WGOT);
    k_wconv<<<512, blk, 0, stream>>>(Wmlp, WMLPB);
    k_wconv<<<256, blk, 0, stream>>>(Wg3, WG3B);
    k_wgi<<<512, blk, 0, stream>>>(Wg1, bg1, Wg2, bg2, WGIB, BIASI);
    k_va<<<256, blk, 0, stream>>>(Wg0, ag0, VA);
    k_va<<<256, blk, 0, stream>>>(Wgo, ago, VA + 512);
    k_wtprep<<<1024, blk, 0, stream>>>(wgt, bia, WT, BT2);
    k_adp<<<1024, blk, 0, stream>>>(nv1, nv2, ADPB);
    k_maskpack<<<128, blk, 0, stream>>>(dg, MASKW);
    k_tin<<<dim3(192, 4, 4), blk, 0, stream>>>(x_in, U1, XTf);
    k_xtt<<<dim3(16, 4, 48), blk, 0, stream>>>(U1, U2);
    // x1 = adp @ x  (Bt = XTT) -> U3 bf16
    k_bgemm<1, 0><<<dim3(8, 2, 48), blk, 0, stream>>>(ADPB, 0, nullptr, 0, 1024, 0, 1024,
        U2, SLAB, nullptr, nullptr, U3, SLAB, nullptr,
        nullptr, nullptr, nullptr, nullptr, nullptr);
    // gcn = [x|x1] @ Wmlp(o,c) + b -> Bf fp32
    k_bgemm<2, 0><<<dim3(8, 2, 48), blk, 0, stream>>>(U1, SLAB, U3, SLAB, 256, 256, 512,
        WMLPB, 0, bmlp, Bf, nullptr, SLAB, nullptr,
        nullptr, nullptr, nullptr, nullptr, nullptr);
    // GAT layer 1
    k_dots<<<12288, blk, 0, stream>>>(U1, VA, W1V, W2V);
    k_w2max<<<48, blk, 0, stream>>>(W2V, W2M);
    k_bgemm<1, 0><<<dim3(2, 8, 48), blk, 0, stream>>>(WG0T, 0, nullptr, 0, 256, 0, 256,
        U1, SLAB, nullptr, nullptr, U4, SLAB, nullptr,
        nullptr, nullptr, nullptr, nullptr, nullptr);
    k_attn_mf<0><<<768, blk, 0, stream>>>(U4, W1V, W2V, W2M, MASKW, U2,
                                          nullptr, nullptr, nullptr, nullptr, nullptr);
    // GAT layer 2
    k_dots<<<12288, blk, 0, stream>>>(U2, VA + 512, W1V, W2V);
    k_w2max<<<48, blk, 0, stream>>>(W2V, W2M);
    k_bgemm<1, 0><<<dim3(2, 8, 48), blk, 0, stream>>>(WGOT, 0, nullptr, 0, 256, 0, 256,
        U2, SLAB, nullptr, nullptr, U4, SLAB, nullptr,
        nullptr, nullptr, nullptr, nullptr, nullptr);
    // attn2 fused epilogue: Af = as*gat + bs*gcn + x, + LN1 partials
    k_attn_mf<1><<<768, blk, 0, stream>>>(U4, W1V, W2V, W2M, MASKW, nullptr,
                                          Bf, XTf, alpha, Af, PART);
    k_stats16<<<48, 64, 0, stream>>>(PART, STATS1);
    k_ln_apply<<<12288, blk, 0, stream>>>((const float4*)Af, STATS1, U3);
    // GLU pair GEMM (interleaved) -> U4 h bf16
    k_bgemm<1, 1><<<dim3(8, 4, 48), blk, 0, stream>>>(U3, SLAB, nullptr, 0, 256, 0, 256,
        WGIB, 0, nullptr, nullptr, U4, SLAB, BIASI,
        nullptr, nullptr, nullptr, nullptr, nullptr);
    // glu3 GEMM + finpre + LN2 partials -> Bf, PART
    k_bgemm<1, 2><<<dim3(8, 2, 48), blk, 0, stream>>>(U4, SLAB, nullptr, 0, 256, 0, 256,
        WG3B, 0, bg3, Bf, nullptr, SLAB, nullptr,
        Af, STATS1, WT, BT2, PART);
    k_stats16<<<48, 64, 0, stream>>>(PART, STATS2);
    k_out<<<dim3(1024, 4), blk, 0, stream>>>(Bf, STATS2, out);
}

// Round 12
// 491.808 us; speedup vs baseline: 12.4336x; 1.1074x over previous
//
#include <hip/hip_runtime.h>
#include <hip/hip_bf16.h>
#include <math.h>

#define DI __device__ __forceinline__
#define AS1 __attribute__((address_space(1)))
#define AS3 __attribute__((address_space(3)))

static constexpr int  B_ = 4, C_ = 256, N_ = 1024, L_ = 12, BL_ = 48;
static constexpr long SLAB = (long)N_ * C_;          // 262144 elems per (b,l)
static constexpr long TOT  = (long)BL_ * SLAB;       // 12,582,912 elems

typedef __attribute__((ext_vector_type(8))) short bf16x8;
typedef __attribute__((ext_vector_type(4))) float f32x4;
typedef __attribute__((ext_vector_type(4))) uint u32x4;

DI float b2f(uint hw) { return __builtin_bit_cast(float, (hw & 0xffffu) << 16); }
DI ushort f2b(float f) {
    uint u = __builtin_bit_cast(uint, f);
    u += 0x7FFFu + ((u >> 16) & 1u);
    return (ushort)(u >> 16);
}
DI uint pack2(float a, float b) {
    __hip_bfloat162 h = __float22bfloat162_rn(make_float2(a, b));
    uint r;
    __builtin_memcpy(&r, &h, 4);
    return r;
}
DI float fexp2(float x) {
#if __has_builtin(__builtin_amdgcn_exp2f)
    return __builtin_amdgcn_exp2f(x);
#else
    return __expf(x * 0.6931471805599453f);
#endif
}

DI void gload16(const void* g, void* l) {
    __builtin_amdgcn_global_load_lds((AS1 uint*)g, (AS3 uint*)l, 16, 0, 0);
}

// ---------------- block reductions (256 threads, 4 waves) ----------------
DI float block_sum256(float v, float* sc) {
    #pragma unroll
    for (int o = 32; o > 0; o >>= 1) v += __shfl_xor(v, o, 64);
    int wid = threadIdx.x >> 6;
    __syncthreads();
    if ((threadIdx.x & 63) == 0) sc[wid] = v;
    __syncthreads();
    return sc[0] + sc[1] + sc[2] + sc[3];
}
DI float block_max256(float v, float* sc) {
    #pragma unroll
    for (int o = 32; o > 0; o >>= 1) v = fmaxf(v, __shfl_xor(v, o, 64));
    int wid = threadIdx.x >> 6;
    __syncthreads();
    if ((threadIdx.x & 63) == 0) sc[wid] = v;
    __syncthreads();
    return fmaxf(fmaxf(sc[0], sc[1]), fmaxf(sc[2], sc[3]));
}

// ---------------- adp = softmax(relu(nv1@nv2), axis=1), bf16 out ----------------
__global__ __launch_bounds__(256) void k_adp(const float* __restrict__ nv1,
                                             const float* __restrict__ nv2,
                                             ushort* __restrict__ adp) {
    __shared__ float r[6];
    __shared__ float sc[4];
    int row = blockIdx.x, tid = threadIdx.x;
    if (tid < 6) r[tid] = nv1[row * 6 + tid];
    __syncthreads();
    float e[4];
    #pragma unroll
    for (int q = 0; q < 4; q++) {
        int j = tid + q * 256;
        float s = 0.f;
        #pragma unroll
        for (int k = 0; k < 6; k++) s += r[k] * nv2[k * 1024 + j];
        e[q] = s > 0.f ? s : 0.f;
    }
    float m = fmaxf(fmaxf(e[0], e[1]), fmaxf(e[2], e[3]));
    m = block_max256(m, sc);
    float ps = 0.f;
    #pragma unroll
    for (int q = 0; q < 4; q++) { e[q] = __expf(e[q] - m); ps += e[q]; }
    ps = block_sum256(ps, sc);
    float rinv = 1.f / ps;
    #pragma unroll
    for (int q = 0; q < 4; q++) adp[(long)row * 1024 + tid + q * 256] = f2b(e[q] * rinv);
}

// ------- transpose in: x[b][c][n][l] -> Xb[(b*12+l)][n][c] bf16 + fp32 copy -------
__global__ __launch_bounds__(256) void k_tin(const float* __restrict__ x,
                                             ushort* __restrict__ xb,
                                             float* __restrict__ xf) {
    __shared__ float t[64][65];
    int nl0 = blockIdx.x * 64, c0 = blockIdx.y * 64, b = blockIdx.z;
    int lx = threadIdx.x & 63, ly = threadIdx.x >> 6;
    #pragma unroll
    for (int i = 0; i < 16; i++) {
        int c = c0 + ly + i * 4;
        t[ly + i * 4][lx] = x[(long)(b * 256 + c) * 12288 + nl0 + lx];
    }
    __syncthreads();
    #pragma unroll
    for (int i = 0; i < 16; i++) {
        int nl = nl0 + ly + i * 4;
        int n = nl / 12, l = nl % 12;
        long idx = ((long)(b * 12 + l) * 1024 + n) * 256 + c0 + lx;
        float v = t[lx][ly + i * 4];
        xb[idx] = f2b(v);
        xf[idx] = v;
    }
}

// ---------------- per-bl transpose Xb[n][c] -> XTT[c][n] (bf16) ----------------
__global__ __launch_bounds__(256) void k_xtt(const ushort* __restrict__ X,
                                             ushort* __restrict__ XT) {
    __shared__ ushort t[64][68];
    int bl = blockIdx.z;
    int n0 = blockIdx.x * 64, c0 = blockIdx.y * 64;
    int lx = threadIdx.x & 63, ly = threadIdx.x >> 6;
    const ushort* Xp = X + (long)bl * SLAB;
    #pragma unroll
    for (int i = 0; i < 16; i++)
        t[ly + i * 4][lx] = Xp[(long)(n0 + ly + i * 4) * 256 + c0 + lx];
    __syncthreads();
    ushort* Tp = XT + (long)bl * SLAB;
    #pragma unroll
    for (int i = 0; i < 16; i++)
        Tp[(long)(c0 + ly + i * 4) * 1024 + n0 + lx] = t[lx][ly + i * 4];
}

// -------- GAT weight transposes 256x256 fp32 [c][o] -> bf16 [o][c] --------
__global__ __launch_bounds__(256) void k_wt2(const float* __restrict__ S0, ushort* __restrict__ D0,
                                             const float* __restrict__ S1, ushort* __restrict__ D1) {
    __shared__ float t[64][65];
    const float* S = blockIdx.z ? S1 : S0;
    ushort* D = blockIdx.z ? D1 : D0;
    int c0 = blockIdx.x * 64, o0 = blockIdx.y * 64;
    int lx = threadIdx.x & 63, ly = threadIdx.x >> 6;
    #pragma unroll
    for (int i = 0; i < 16; i++)
        t[ly + i * 4][lx] = S[(long)(c0 + ly + i * 4) * 256 + o0 + lx];
    __syncthreads();
    #pragma unroll
    for (int i = 0; i < 16; i++)
        D[(long)(o0 + ly + i * 4) * 256 + c0 + lx] = f2b(t[lx][ly + i * 4]);
}

// ---------------- fp32 -> bf16 straight cast ----------------
__global__ __launch_bounds__(256) void k_wconv(const float* __restrict__ S, ushort* __restrict__ D) {
    long i = (long)blockIdx.x * 256 + threadIdx.x;
    D[i] = f2b(S[i]);
}

// ------- interleaved GLU weights: WGI[p*32+q] = (q<16 ? Wg1 : Wg2) row p*16+q%16 -------
__global__ __launch_bounds__(256) void k_wgi(const float* __restrict__ W1, const float* __restrict__ b1,
                                             const float* __restrict__ W2, const float* __restrict__ b2,
                                             ushort* __restrict__ WGI, float* __restrict__ BI) {
    int n = blockIdx.x, p = n >> 5, q = n & 31;
    const float* src = (q < 16) ? W1 + (long)(p * 16 + q) * 256
                                : W2 + (long)(p * 16 + q - 16) * 256;
    WGI[(long)n * 256 + threadIdx.x] = f2b(src[threadIdx.x]);
    if (threadIdx.x == 0) BI[n] = (q < 16) ? b1[p * 16 + q] : b2[p * 16 + q - 16];
}

// ----- va = W @ a pair -----
__global__ __launch_bounds__(256) void k_va(const float* __restrict__ W, const float* __restrict__ a,
                                            float* __restrict__ va) {
    __shared__ float sc[4];
    int c = blockIdx.x, t = threadIdx.x;
    float w = W[(long)c * 256 + t];
    float s1 = block_sum256(w * a[t], sc);
    float s2 = block_sum256(w * a[256 + t], sc);
    if (t == 0) { va[c] = s1; va[256 + c] = s2; }
}

// ------- weight/bias prep: wt[n][c] = w[c][n]+1, bt[n][c] = b[c][n] -------
__global__ __launch_bounds__(256) void k_wtprep(const float* __restrict__ w,
                                                const float* __restrict__ b,
                                                float* __restrict__ wt,
                                                float* __restrict__ bt) {
    int n = blockIdx.x, c = threadIdx.x;
    wt[(long)n * 256 + c] = w[(long)c * 1024 + n] + 1.f;
    bt[(long)n * 256 + c] = b[(long)c * 1024 + n];
}

// ------- pack mask bits -------
__global__ __launch_bounds__(256) void k_maskpack(const int* __restrict__ dg,
                                                  uint* __restrict__ maskw) {
    int w = blockIdx.x * 256 + threadIdx.x;
    int row = w >> 5, wo = w & 31;
    uint m = 0;
    #pragma unroll
    for (int b = 0; b < 32; b++)
        m |= (dg[(long)row * 1024 + wo * 32 + b] > 0 ? 1u : 0u) << b;
    maskw[w] = m;
}

// ------- bf16 MFMA GEMM, 2-phase pipelined -------
// GLU=0: plain (+bias) -> Cf/Cb. GLU=1: interleaved g1/g2, h=g1*sig(g2) -> Cb.
// GLU=2: finpre fusion: v=(acc+bias + (FA-m1)*r1)*WTp + BTp -> Cf, + LN partials.
template<int NPAIR, int GLU>
__global__ __launch_bounds__(256) void k_bgemm(
    const ushort* __restrict__ A0, long sA0,
    const ushort* __restrict__ A1, long sA1,
    int lda, int K0, int KK,
    const ushort* __restrict__ Bt, long sBt,
    const float* __restrict__ bias,
    float* __restrict__ Cf, ushort* __restrict__ Cb, long sC,
    const float* __restrict__ biasi,
    const float* __restrict__ FA, const float2* __restrict__ ST1,
    const float* __restrict__ WTp, const float* __restrict__ BTp,
    float2* __restrict__ partOut) {
    __shared__ ushort As[2][128 * 32];
    __shared__ ushort Bs[2][128 * 32];
    __shared__ float sc[4];
    const int tid = threadIdx.x;
    const int bl = blockIdx.z;
    const int m0 = blockIdx.x * 128, n0 = blockIdx.y * 128;
    const int N = gridDim.y * 128;
    const int lane = tid & 63, w = tid >> 6;
    const int wm = (w >> 1) * 64, wn = (w & 1) * 64;
    const int sr = tid >> 2, sk = (tid & 3) * 8;
    const int fr = lane & 15, fk = (lane >> 4) * 8;
    f32x4 acc[4][4] = {};
    const ushort* Ab0 = A0 + (long)bl * sA0;
    const ushort* Ab1 = (NPAIR == 2) ? A1 + (long)bl * sA1 : nullptr;
    const ushort* Bb = Bt + (long)bl * sBt;

    auto stage = [&](int buf, int k0) {
        const ushort* Asrc = Ab0; int kl = k0;
        if (NPAIR == 2 && k0 >= K0) { Asrc = Ab1; kl = k0 - K0; }
        gload16(&Asrc[(long)(m0 + sr) * lda + kl + sk],      &As[buf][sr * 32 + sk]);
        gload16(&Asrc[(long)(m0 + sr + 64) * lda + kl + sk], &As[buf][(sr + 64) * 32 + sk]);
        gload16(&Bb[(long)(n0 + sr) * KK + k0 + sk],         &Bs[buf][sr * 32 + sk]);
        gload16(&Bb[(long)(n0 + sr + 64) * KK + k0 + sk],    &Bs[buf][(sr + 64) * 32 + sk]);
    };
    auto compute = [&](int buf) {
        bf16x8 af[4], bg[4];
        #pragma unroll
        for (int i = 0; i < 4; i++) {
            af[i] = *(const bf16x8*)&As[buf][(wm + i * 16 + fr) * 32 + fk];
            bg[i] = *(const bf16x8*)&Bs[buf][(wn + i * 16 + fr) * 32 + fk];
        }
        #pragma unroll
        for (int i = 0; i < 4; i++)
            #pragma unroll
            for (int j = 0; j < 4; j++)
                acc[i][j] = __builtin_amdgcn_mfma_f32_16x16x32_bf16(af[i], bg[j], acc[i][j], 0, 0, 0);
    };

    stage(0, 0);
    __syncthreads();
    int cur = 0;
    for (int k0 = 32; k0 < KK; k0 += 32) {
        stage(cur ^ 1, k0);
        compute(cur);
        __syncthreads();
        cur ^= 1;
    }
    compute(cur);

    const int cn = lane & 15, rb = (lane >> 4) * 4;
    if (GLU == 1) {
        #pragma unroll
        for (int nt = 0; nt < 4; nt += 2) {
            int n1 = n0 + wn + nt * 16 + cn;
            int hcol = ((n1 >> 5) << 4) + cn;
            float b1 = biasi[n1], b2 = biasi[n1 + 16];
            #pragma unroll
            for (int i = 0; i < 4; i++) {
                #pragma unroll
                for (int r = 0; r < 4; r++) {
                    int m = m0 + wm + i * 16 + rb + r;
                    float g1 = acc[i][nt][r] + b1;
                    float g2 = acc[i][nt + 1][r] + b2;
                    float h = g1 / (1.f + __expf(-g2));
                    Cb[(long)bl * sC + (long)m * 256 + hcol] = f2b(h);
                }
            }
        }
    } else if (GLU == 2) {
        float2 st = ST1[bl];
        float ssum = 0.f, qsum = 0.f;
        #pragma unroll
        for (int j = 0; j < 4; j++) {
            int n = n0 + wn + j * 16 + cn;
            float bv = bias[n];
            #pragma unroll
            for (int i = 0; i < 4; i++) {
                #pragma unroll
                for (int r = 0; r < 4; r++) {
                    int m = m0 + wm + i * 16 + rb + r;
                    long idx = (long)bl * sC + (long)m * N + n;
                    float xn = (FA[idx] - st.x) * st.y;
                    float v = (acc[i][j][r] + bv + xn) * WTp[m * 256 + n] + BTp[m * 256 + n];
                    Cf[idx] = v;
                    ssum += v;
                    qsum += v * v;
                }
            }
        }
        ssum = block_sum256(ssum, sc);
        qsum = block_sum256(qsum, sc);
        if (tid == 0)
            partOut[bl * 16 + blockIdx.x * 2 + blockIdx.y] = make_float2(ssum, qsum);
    } else {
        #pragma unroll
        for (int j = 0; j < 4; j++) {
            int n = n0 + wn + j * 16 + cn;
            float bv = bias ? bias[n] : 0.f;
            #pragma unroll
            for (int i = 0; i < 4; i++) {
                #pragma unroll
                for (int r = 0; r < 4; r++) {
                    int m = m0 + wm + i * 16 + rb + r;
                    float v = acc[i][j][r] + bv;
                    long idx = (long)bl * sC + (long)m * N + n;
                    if (Cf) Cf[idx] = v;
                    if (Cb) Cb[idx] = f2b(v);
                }
            }
        }
    }
}

// ---------------- w1/w2 GEMV ----------------
__global__ __launch_bounds__(256) void k_dots(const ushort* __restrict__ X,
                                              const float* __restrict__ va,
                                              float* __restrict__ o1,
                                              float* __restrict__ o2) {
    int wid = threadIdx.x >> 6, lane = threadIdx.x & 63;
    long row = (long)blockIdx.x * 4 + wid;
    uint2 xv = *(const uint2*)(X + row * 256 + lane * 4);
    float x0 = b2f(xv.x), x1 = b2f(xv.x >> 16), x2 = b2f(xv.y), x3 = b2f(xv.y >> 16);
    float4 v1 = *(const float4*)&va[lane * 4];
    float4 v2 = *(const float4*)&va[256 + lane * 4];
    float s1 = x0 * v1.x + x1 * v1.y + x2 * v1.z + x3 * v1.w;
    float s2 = x0 * v2.x + x1 * v2.y + x2 * v2.z + x3 * v2.w;
    #pragma unroll
    for (int o = 32; o > 0; o >>= 1) { s1 += __shfl_xor(s1, o, 64); s2 += __shfl_xor(s2, o, 64); }
    if (lane == 0) { o1[row] = s1; o2[row] = s2; }
}

// ------- per-bl global max of w2 -------
__global__ __launch_bounds__(256) void k_w2max(const float* __restrict__ w2v,
                                               float* __restrict__ w2m) {
    __shared__ float sc[4];
    int bl = blockIdx.x;
    float4 v = *(const float4*)&w2v[(long)bl * 1024 + threadIdx.x * 4];
    float m = fmaxf(fmaxf(v.x, v.y), fmaxf(v.z, v.w));
    m = block_max256(m, sc);
    if (threadIdx.x == 0) w2m[bl] = m;
}

// ------- MFMA attention v7: barrier-free + VALU diet -------
// p = exp2(max(w1m + w2L[j], w1n + w2N[j])); mask via 4-entry LUT AND on packed bf16;
// row-sums via extra MFMA against constant all-ones B-fragment (no cross-lane at all).
// FUSE=1: epilogue computes as*elu(out)+bs*gcn+x -> Af fp32 + LN partials.
template<int FUSE>
__global__ __launch_bounds__(256, 3) void k_attn_mf(
    const ushort* __restrict__ WhT,   // [48][256][1024] bf16
    const float* __restrict__ w1v, const float* __restrict__ w2v,
    const float* __restrict__ w2m,    // [48]
    const uint* __restrict__ maskw,   // [1024][32]
    ushort* __restrict__ outB,
    const float* __restrict__ gcn, const float* __restrict__ xf,
    const float* __restrict__ alpha,
    float* __restrict__ outF, float2* __restrict__ part) {
    __shared__ float w2L[1024];          // w2 * log2e
    __shared__ float w2N[1024];          // 0.2 * w2 * log2e
    __shared__ uint msk[64 * 33];        // padded stride 33
    __shared__ uint mlut[4];             // 2-bit mask -> halfword AND pattern
    __shared__ float sc[4];
    constexpr float LOG2E = 1.4426950408889634f;
    int d = blockIdx.x;                  // 768 blocks
    int lidx = (d & 7) * 96 + (d >> 3);  // XCD-chunked: 6 bl per XCD
    int bl = lidx >> 4;
    int i0 = (lidx & 15) * 64;
    int tid = threadIdx.x;
    #pragma unroll
    for (int q = 0; q < 4; q++) {
        float v = w2v[(long)bl * 1024 + tid + q * 256];
        w2L[tid + q * 256] = v * LOG2E;
        w2N[tid + q * 256] = v * (0.2f * LOG2E);
    }
    if (tid < 4) mlut[tid] = ((tid & 1) ? 0x0000FFFFu : 0u) | ((tid & 2) ? 0xFFFF0000u : 0u);
    {   // mask staging: 2048 words, coalesced, padded stride
        const uint4* gm = (const uint4*)(maskw + (long)i0 * 32);
        uint4 ma = gm[tid * 2], mb = gm[tid * 2 + 1];
        int r0 = tid >> 2, w0 = (tid & 3) * 8;
        uint* mp = &msk[r0 * 33 + w0];
        mp[0] = ma.x; mp[1] = ma.y; mp[2] = ma.z; mp[3] = ma.w;
        mp[4] = mb.x; mp[5] = mb.y; mp[6] = mb.z; mp[7] = mb.w;
    }
    __syncthreads();
    const int lane = tid & 63, w = tid >> 6;
    const int wn = w * 64;
    const int fr = lane & 15, fg = lane >> 4, fk8 = fg * 8;
    const float w2mL = w2m[bl] * LOG2E;
    float w1m[4], w1n[4];
    #pragma unroll
    for (int mt = 0; mt < 4; mt++) {
        float w1L = w1v[(long)bl * 1024 + i0 + mt * 16 + fr] * LOG2E;
        float e0 = w1L + w2mL;
        float mrL = fmaxf(e0, 0.2f * e0);          // = log2e * leaky(w1+w2max) >= all scores
        w1m[mt] = w1L - mrL;
        w1n[mt] = 0.2f * w1L - mrL;
    }
    f32x4 acc[4][4] = {};
    f32x4 acc_s[4] = {};
    u32x4 ov; ov[0] = ov[1] = ov[2] = ov[3] = 0x3F803F80u;   // bf16 1.0 pairs
    const bf16x8 onesf = __builtin_bit_cast(bf16x8, ov);
    const ushort* bp = WhT + (long)bl * SLAB;
    #pragma unroll 1
    for (int ks = 0; ks < 32; ks++) {
        bf16x8 bg[4];
        #pragma unroll
        for (int nt = 0; nt < 4; nt++)
            bg[nt] = *(const bf16x8*)&bp[(long)(wn + nt * 16 + fr) * 1024 + ks * 32 + fk8];
        float4 wa = *(const float4*)&w2L[ks * 32 + fk8];
        float4 wb = *(const float4*)&w2L[ks * 32 + fk8 + 4];
        float4 na = *(const float4*)&w2N[ks * 32 + fk8];
        float4 nb = *(const float4*)&w2N[ks * 32 + fk8 + 4];
        #pragma unroll
        for (int mt = 0; mt < 4; mt++) {
            uint mby = (msk[(mt * 16 + fr) * 33 + ks] >> (fg * 8)) & 0xffu;
            float p0 = fexp2(fmaxf(w1m[mt] + wa.x, w1n[mt] + na.x));
            float p1 = fexp2(fmaxf(w1m[mt] + wa.y, w1n[mt] + na.y));
            float p2 = fexp2(fmaxf(w1m[mt] + wa.z, w1n[mt] + na.z));
            float p3 = fexp2(fmaxf(w1m[mt] + wa.w, w1n[mt] + na.w));
            float p4 = fexp2(fmaxf(w1m[mt] + wb.x, w1n[mt] + nb.x));
            float p5 = fexp2(fmaxf(w1m[mt] + wb.y, w1n[mt] + nb.y));
            float p6 = fexp2(fmaxf(w1m[mt] + wb.z, w1n[mt] + nb.z));
            float p7 = fexp2(fmaxf(w1m[mt] + wb.w, w1n[mt] + nb.w));
            u32x4 av;
            av[0] = pack2(p0, p1) & mlut[mby & 3];
            av[1] = pack2(p2, p3) & mlut[(mby >> 2) & 3];
            av[2] = pack2(p4, p5) & mlut[(mby >> 4) & 3];
            av[3] = pack2(p6, p7) & mlut[(mby >> 6) & 3];
            bf16x8 af = __builtin_bit_cast(bf16x8, av);
            acc_s[mt] = __builtin_amdgcn_mfma_f32_16x16x32_bf16(af, onesf, acc_s[mt], 0, 0, 0);
            #pragma unroll
            for (int nt = 0; nt < 4; nt++)
                acc[mt][nt] = __builtin_amdgcn_mfma_f32_16x16x32_bf16(
                    af, bg[nt], acc[mt][nt], 0, 0, 0);
        }
    }
    float as = 0.f, bs = 0.f, ssum = 0.f, qsum = 0.f;
    if (FUSE) { as = 1.f / (1.f + __expf(-alpha[0])); bs = 1.f - as; }
    #pragma unroll
    for (int mt = 0; mt < 4; mt++) {
        #pragma unroll
        for (int r = 0; r < 4; r++) {
            float si = 1.f / acc_s[mt][r];          // own row's sum — no cross-lane
            int i = mt * 16 + fg * 4 + r;
            #pragma unroll
            for (int nt = 0; nt < 4; nt++) {
                int c = wn + nt * 16 + fr;
                float v = acc[mt][nt][r] * si;
                v = (v > 0.f) ? v : __expf(v) - 1.f;       // elu
                long idx = (long)bl * SLAB + (long)(i0 + i) * 256 + c;
                if (FUSE) {
                    float fv = as * v + bs * gcn[idx] + xf[idx];
                    outF[idx] = fv;
                    ssum += fv;
                    qsum += fv * fv;
                } else {
                    outB[idx] = f2b(v);
                }
            }
        }
    }
    if (FUSE) {
        ssum = block_sum256(ssum, sc);
        qsum = block_sum256(qsum, sc);
        if (tid == 0) part[bl * 16 + (lidx & 15)] = make_float2(ssum, qsum);
    }
}

// ------- stats from 16 partials per slab -------
__global__ void k_stats16(const float2* __restrict__ part, float2* __restrict__ stats) {
    int bl = blockIdx.x, t = threadIdx.x;
    float s = 0.f, q = 0.f;
    if (t < 16) { float2 v = part[bl * 16 + t]; s = v.x; q = v.y; }
    #pragma unroll
    for (int o = 8; o > 0; o >>= 1) { s += __shfl_xor(s, o, 64); q += __shfl_xor(q, o, 64); }
    if (t == 0) {
        float mean = s / (float)SLAB;
        float var = q / (float)SLAB - mean * mean;
        stats[bl] = make_float2(mean, 1.f / sqrtf(var + 1e-5f));
    }
}

// ------- LN apply, bf16 out only -------
__global__ __launch_bounds__(256) void k_ln_apply(const float4* __restrict__ x,
                                                  const float2* __restrict__ stats,
                                                  ushort* __restrict__ ob) {
    long i = (long)blockIdx.x * 256 + threadIdx.x;
    int bl = (int)(i >> 16);
    float2 st = stats[bl];
    float4 v = x[i];
    uint2 ow;
    ow.x = pack2((v.x - st.x) * st.y, (v.y - st.x) * st.y);
    ow.y = pack2((v.z - st.x) * st.y, (v.w - st.x) * st.y);
    ((uint2*)ob)[i] = ow;
}

// ------- final normalize + transpose back to [b][c][n][l] -------
__global__ __launch_bounds__(256) void k_out(const float* __restrict__ x,
                                             const float2* __restrict__ stats,
                                             float* __restrict__ out) {
    int n = blockIdx.x, b = blockIdx.y, c = threadIdx.x;
    float v[12];
    #pragma unroll
    for (int l = 0; l < 12; l++) {
        float2 st = stats[b * 12 + l];
        float t = x[(long)(b * 12 + l) * SLAB + (long)n * 256 + c];
        v[l] = (t - st.x) * st.y;
    }
    float4* op = (float4*)(out + ((long)(b * 256 + c) * 1024 + n) * 12);
    op[0] = make_float4(v[0], v[1], v[2], v[3]);
    op[1] = make_float4(v[4], v[5], v[6], v[7]);
    op[2] = make_float4(v[8], v[9], v[10], v[11]);
}

// =================================================================
extern "C" void kernel_launch(void* const* d_in, const int* in_sizes, int n_in,
                              void* d_out, int out_size, void* d_ws, size_t ws_size,
                              hipStream_t stream) {
    (void)in_sizes; (void)n_in; (void)out_size; (void)ws_size;
    const float* x_in = (const float*)d_in[0];
    const int*   dg   = (const int*)d_in[1];
    const float* nv1  = (const float*)d_in[2];
    const float* nv2  = (const float*)d_in[3];
    const float* Wmlp = (const float*)d_in[4];
    const float* bmlp = (const float*)d_in[5];
    const float* Wg0  = (const float*)d_in[6];
    const float* ag0  = (const float*)d_in[7];
    const float* Wgo  = (const float*)d_in[8];
    const float* ago  = (const float*)d_in[9];
    const float* Wg1  = (const float*)d_in[10];
    const float* bg1  = (const float*)d_in[11];
    const float* Wg2  = (const float*)d_in[12];
    const float* bg2  = (const float*)d_in[13];
    const float* Wg3  = (const float*)d_in[14];
    const float* bg3  = (const float*)d_in[15];
    const float* alpha = (const float*)d_in[16];
    const float* wgt  = (const float*)d_in[17];
    const float* bia  = (const float*)d_in[18];
    float* out = (float*)d_out;

    // ---- workspace (~208 MB; Af aliases the dead U1+U2 region) ----
    float* XTf = (float*)d_ws;          // fp32 x_in copy
    float* Bf  = XTf + TOT;             // fp32 gcn; later final pre-LN
    ushort* U1 = (ushort*)(Bf + TOT);   // Xb bf16
    ushort* U2 = U1 + TOT;              // XTT; later g (attn1 out)
    float* Af  = (float*)U1;            // fp32 fuse output, live after U1/U2 dead
    ushort* U3 = U2 + TOT;              // x1b; later xn bf16
    ushort* U4 = U3 + TOT;              // WhT; later h bf16
    ushort* ADPB = U4 + TOT;            // [1024][1024]
    ushort* WMLPB = ADPB + (long)1024 * 1024;
    ushort* WG0T = WMLPB + 131072;
    ushort* WGOT = WG0T + 65536;
    ushort* WGIB = WGOT + 65536;        // [512][256] interleaved g1/g2
    ushort* WG3B = WGIB + 131072;
    float* BIASI = (float*)(WG3B + 65536);  // 512
    float* VA = BIASI + 512;                // 1024
    float* W1V = VA + 1024;
    float* W2V = W1V + 49152;
    float* W2M = W2V + 49152;               // 48 (+pad)
    uint* MASKW = (uint*)(W2M + 64);        // 32768
    float2* PART = (float2*)(MASKW + 32768); // [48][16]
    float2* STATS1 = PART + 48 * 16;
    float2* STATS2 = STATS1 + 48;
    float* WT = (float*)(STATS2 + 48);
    float* BT2 = WT + SLAB;

    dim3 blk(256);
    // prep
    k_wt2<<<dim3(4, 4, 2), blk, 0, stream>>>(Wg0, WG0T, Wgo, WGOT);
    k_wconv<<<512, blk, 0, stream>>>(Wmlp, WMLPB);
    k_wconv<<<256, blk, 0, stream>>>(Wg3, WG3B);
    k_wgi<<<512, blk, 0, stream>>>(Wg1, bg1, Wg2, bg2, WGIB, BIASI);
    k_va<<<256, blk, 0, stream>>>(Wg0, ag0, VA);
    k_va<<<256, blk, 0, stream>>>(Wgo, ago, VA + 512);
    k_wtprep<<<1024, blk, 0, stream>>>(wgt, bia, WT, BT2);
    k_adp<<<1024, blk, 0, stream>>>(nv1, nv2, ADPB);
    k_maskpack<<<128, blk, 0, stream>>>(dg, MASKW);
    k_tin<<<dim3(192, 4, 4), blk, 0, stream>>>(x_in, U1, XTf);
    k_xtt<<<dim3(16, 4, 48), blk, 0, stream>>>(U1, U2);
    // x1 = adp @ x  (Bt = XTT) -> U3 bf16
    k_bgemm<1, 0><<<dim3(8, 2, 48), blk, 0, stream>>>(ADPB, 0, nullptr, 0, 1024, 0, 1024,
        U2, SLAB, nullptr, nullptr, U3, SLAB, nullptr,
        nullptr, nullptr, nullptr, nullptr, nullptr);
    // gcn = [x|x1] @ Wmlp(o,c) + b -> Bf fp32
    k_bgemm<2, 0><<<dim3(8, 2, 48), blk, 0, stream>>>(U1, SLAB, U3, SLAB, 256, 256, 512,
        WMLPB, 0, bmlp, Bf, nullptr, SLAB, nullptr,
        nullptr, nullptr, nullptr, nullptr, nullptr);
    // GAT layer 1
    k_dots<<<12288, blk, 0, stream>>>(U1, VA, W1V, W2V);
    k_w2max<<<48, blk, 0, stream>>>(W2V, W2M);
    k_bgemm<1, 0><<<dim3(2, 8, 48), blk, 0, stream>>>(WG0T, 0, nullptr, 0, 256, 0, 256,
        U1, SLAB, nullptr, nullptr, U4, SLAB, nullptr,
        nullptr, nullptr, nullptr, nullptr, nullptr);
    k_attn_mf<0><<<768, blk, 0, stream>>>(U4, W1V, W2V, W2M, MASKW, U2,
                                          nullptr, nullptr, nullptr, nullptr, nullptr);
    // GAT layer 2
    k_dots<<<12288, blk, 0, stream>>>(U2, VA + 512, W1V, W2V);
    k_w2max<<<48, blk, 0, stream>>>(W2V, W2M);
    k_bgemm<1, 0><<<dim3(2, 8, 48), blk, 0, stream>>>(WGOT, 0, nullptr, 0, 256, 0, 256,
        U2, SLAB, nullptr, nullptr, U4, SLAB, nullptr,
        nullptr, nullptr, nullptr, nullptr, nullptr);
    // attn2 fused epilogue: Af = as*gat + bs*gcn + x, + LN1 partials
    k_attn_mf<1><<<768, blk, 0, stream>>>(U4, W1V, W2V, W2M, MASKW, nullptr,
                                          Bf, XTf, alpha, Af, PART);
    k_stats16<<<48, 64, 0, stream>>>(PART, STATS1);
    k_ln_apply<<<12288, blk, 0, stream>>>((const float4*)Af, STATS1, U3);
    // GLU pair GEMM (interleaved) -> U4 h bf16
    k_bgemm<1, 1><<<dim3(8, 4, 48), blk, 0, stream>>>(U3, SLAB, nullptr, 0, 256, 0, 256,
        WGIB, 0, nullptr, nullptr, U4, SLAB, BIASI,
        nullptr, nullptr, nullptr, nullptr, nullptr);
    // glu3 GEMM + finpre + LN2 partials -> Bf, PART
    k_bgemm<1, 2><<<dim3(8, 2, 48), blk, 0, stream>>>(U4, SLAB, nullptr, 0, 256, 0, 256,
        WG3B, 0, bg3, Bf, nullptr, SLAB, nullptr,
        Af, STATS1, WT, BT2, PART);
    k_stats16<<<48, 64, 0, stream>>>(PART, STATS2);
    k_out<<<dim3(1024, 4), blk, 0, stream>>>(Bf, STATS2, out);
}

// Round 13
// 484.007 us; speedup vs baseline: 12.6340x; 1.0161x over previous
//
#include <hip/hip_runtime.h>
#include <hip/hip_bf16.h>
#include <math.h>

#define DI __device__ __forceinline__
#define AS1 __attribute__((address_space(1)))
#define AS3 __attribute__((address_space(3)))

static constexpr int  B_ = 4, C_ = 256, N_ = 1024, L_ = 12, BL_ = 48;
static constexpr long SLAB = (long)N_ * C_;          // 262144 elems per (b,l)
static constexpr long TOT  = (long)BL_ * SLAB;       // 12,582,912 elems

typedef __attribute__((ext_vector_type(8))) short bf16x8;
typedef __attribute__((ext_vector_type(4))) float f32x4;
typedef __attribute__((ext_vector_type(4))) uint u32x4;

DI float b2f(uint hw) { return __builtin_bit_cast(float, (hw & 0xffffu) << 16); }
DI ushort f2b(float f) {
    uint u = __builtin_bit_cast(uint, f);
    u += 0x7FFFu + ((u >> 16) & 1u);
    return (ushort)(u >> 16);
}
DI uint pack2(float a, float b) {
    __hip_bfloat162 h = __float22bfloat162_rn(make_float2(a, b));
    uint r;
    __builtin_memcpy(&r, &h, 4);
    return r;
}
DI float fexp2(float x) {
#if __has_builtin(__builtin_amdgcn_exp2f)
    return __builtin_amdgcn_exp2f(x);
#else
    return __expf(x * 0.6931471805599453f);
#endif
}

DI void gload16(const void* g, void* l) {
    __builtin_amdgcn_global_load_lds((AS1 uint*)g, (AS3 uint*)l, 16, 0, 0);
}

// ---------------- block reductions (256 threads, 4 waves) ----------------
DI float block_sum256(float v, float* sc) {
    #pragma unroll
    for (int o = 32; o > 0; o >>= 1) v += __shfl_xor(v, o, 64);
    int wid = threadIdx.x >> 6;
    __syncthreads();
    if ((threadIdx.x & 63) == 0) sc[wid] = v;
    __syncthreads();
    return sc[0] + sc[1] + sc[2] + sc[3];
}
DI float block_max256(float v, float* sc) {
    #pragma unroll
    for (int o = 32; o > 0; o >>= 1) v = fmaxf(v, __shfl_xor(v, o, 64));
    int wid = threadIdx.x >> 6;
    __syncthreads();
    if ((threadIdx.x & 63) == 0) sc[wid] = v;
    __syncthreads();
    return fmaxf(fmaxf(sc[0], sc[1]), fmaxf(sc[2], sc[3]));
}

// ---------------- adp = softmax(relu(nv1@nv2), axis=1), bf16 out ----------------
__global__ __launch_bounds__(256) void k_adp(const float* __restrict__ nv1,
                                             const float* __restrict__ nv2,
                                             ushort* __restrict__ adp) {
    __shared__ float r[6];
    __shared__ float sc[4];
    int row = blockIdx.x, tid = threadIdx.x;
    if (tid < 6) r[tid] = nv1[row * 6 + tid];
    __syncthreads();
    float e[4];
    #pragma unroll
    for (int q = 0; q < 4; q++) {
        int j = tid + q * 256;
        float s = 0.f;
        #pragma unroll
        for (int k = 0; k < 6; k++) s += r[k] * nv2[k * 1024 + j];
        e[q] = s > 0.f ? s : 0.f;
    }
    float m = fmaxf(fmaxf(e[0], e[1]), fmaxf(e[2], e[3]));
    m = block_max256(m, sc);
    float ps = 0.f;
    #pragma unroll
    for (int q = 0; q < 4; q++) { e[q] = __expf(e[q] - m); ps += e[q]; }
    ps = block_sum256(ps, sc);
    float rinv = 1.f / ps;
    #pragma unroll
    for (int q = 0; q < 4; q++) adp[(long)row * 1024 + tid + q * 256] = f2b(e[q] * rinv);
}

// ------- transpose in: x[b][c][n][l] -> Xb[(b*12+l)][n][c] bf16 + fp32 copy -------
__global__ __launch_bounds__(256) void k_tin(const float* __restrict__ x,
                                             ushort* __restrict__ xb,
                                             float* __restrict__ xf) {
    __shared__ float t[64][65];
    int nl0 = blockIdx.x * 64, c0 = blockIdx.y * 64, b = blockIdx.z;
    int lx = threadIdx.x & 63, ly = threadIdx.x >> 6;
    #pragma unroll
    for (int i = 0; i < 16; i++) {
        int c = c0 + ly + i * 4;
        t[ly + i * 4][lx] = x[(long)(b * 256 + c) * 12288 + nl0 + lx];
    }
    __syncthreads();
    #pragma unroll
    for (int i = 0; i < 16; i++) {
        int nl = nl0 + ly + i * 4;
        int n = nl / 12, l = nl % 12;
        long idx = ((long)(b * 12 + l) * 1024 + n) * 256 + c0 + lx;
        float v = t[lx][ly + i * 4];
        xb[idx] = f2b(v);
        xf[idx] = v;
    }
}

// ---------------- per-bl transpose Xb[n][c] -> XTT[c][n] (bf16) ----------------
__global__ __launch_bounds__(256) void k_xtt(const ushort* __restrict__ X,
                                             ushort* __restrict__ XT) {
    __shared__ ushort t[64][68];
    int bl = blockIdx.z;
    int n0 = blockIdx.x * 64, c0 = blockIdx.y * 64;
    int lx = threadIdx.x & 63, ly = threadIdx.x >> 6;
    const ushort* Xp = X + (long)bl * SLAB;
    #pragma unroll
    for (int i = 0; i < 16; i++)
        t[ly + i * 4][lx] = Xp[(long)(n0 + ly + i * 4) * 256 + c0 + lx];
    __syncthreads();
    ushort* Tp = XT + (long)bl * SLAB;
    #pragma unroll
    for (int i = 0; i < 16; i++)
        Tp[(long)(c0 + ly + i * 4) * 1024 + n0 + lx] = t[lx][ly + i * 4];
}

// -------- GAT weight transposes 256x256 fp32 [c][o] -> bf16 [o][c] --------
__global__ __launch_bounds__(256) void k_wt2(const float* __restrict__ S0, ushort* __restrict__ D0,
                                             const float* __restrict__ S1, ushort* __restrict__ D1) {
    __shared__ float t[64][65];
    const float* S = blockIdx.z ? S1 : S0;
    ushort* D = blockIdx.z ? D1 : D0;
    int c0 = blockIdx.x * 64, o0 = blockIdx.y * 64;
    int lx = threadIdx.x & 63, ly = threadIdx.x >> 6;
    #pragma unroll
    for (int i = 0; i < 16; i++)
        t[ly + i * 4][lx] = S[(long)(c0 + ly + i * 4) * 256 + o0 + lx];
    __syncthreads();
    #pragma unroll
    for (int i = 0; i < 16; i++)
        D[(long)(o0 + ly + i * 4) * 256 + c0 + lx] = f2b(t[lx][ly + i * 4]);
}

// ---------------- fp32 -> bf16 straight cast ----------------
__global__ __launch_bounds__(256) void k_wconv(const float* __restrict__ S, ushort* __restrict__ D) {
    long i = (long)blockIdx.x * 256 + threadIdx.x;
    D[i] = f2b(S[i]);
}

// ------- interleaved GLU weights: WGI[p*32+q] = (q<16 ? Wg1 : Wg2) row p*16+q%16 -------
__global__ __launch_bounds__(256) void k_wgi(const float* __restrict__ W1, const float* __restrict__ b1,
                                             const float* __restrict__ W2, const float* __restrict__ b2,
                                             ushort* __restrict__ WGI, float* __restrict__ BI) {
    int n = blockIdx.x, p = n >> 5, q = n & 31;
    const float* src = (q < 16) ? W1 + (long)(p * 16 + q) * 256
                                : W2 + (long)(p * 16 + q - 16) * 256;
    WGI[(long)n * 256 + threadIdx.x] = f2b(src[threadIdx.x]);
    if (threadIdx.x == 0) BI[n] = (q < 16) ? b1[p * 16 + q] : b2[p * 16 + q - 16];
}

// ----- va = W @ a pair -----
__global__ __launch_bounds__(256) void k_va(const float* __restrict__ W, const float* __restrict__ a,
                                            float* __restrict__ va) {
    __shared__ float sc[4];
    int c = blockIdx.x, t = threadIdx.x;
    float w = W[(long)c * 256 + t];
    float s1 = block_sum256(w * a[t], sc);
    float s2 = block_sum256(w * a[256 + t], sc);
    if (t == 0) { va[c] = s1; va[256 + c] = s2; }
}

// ------- weight/bias prep: wt[n][c] = w[c][n]+1, bt[n][c] = b[c][n] -------
__global__ __launch_bounds__(256) void k_wtprep(const float* __restrict__ w,
                                                const float* __restrict__ b,
                                                float* __restrict__ wt,
                                                float* __restrict__ bt) {
    int n = blockIdx.x, c = threadIdx.x;
    wt[(long)n * 256 + c] = w[(long)c * 1024 + n] + 1.f;
    bt[(long)n * 256 + c] = b[(long)c * 1024 + n];
}

// ------- pack mask bits -------
__global__ __launch_bounds__(256) void k_maskpack(const int* __restrict__ dg,
                                                  uint* __restrict__ maskw) {
    int w = blockIdx.x * 256 + threadIdx.x;
    int row = w >> 5, wo = w & 31;
    uint m = 0;
    #pragma unroll
    for (int b = 0; b < 32; b++)
        m |= (dg[(long)row * 1024 + wo * 32 + b] > 0 ? 1u : 0u) << b;
    maskw[w] = m;
}

// ------- bf16 MFMA GEMM, 2-phase pipelined -------
// GLU=0: plain (+bias) -> Cf/Cb. GLU=1: interleaved g1/g2, h=g1*sig(g2) -> Cb.
// GLU=2: finpre fusion: v=(acc+bias + (FA-m1)*r1)*WTp + BTp -> Cf, + LN partials.
template<int NPAIR, int GLU>
__global__ __launch_bounds__(256) void k_bgemm(
    const ushort* __restrict__ A0, long sA0,
    const ushort* __restrict__ A1, long sA1,
    int lda, int K0, int KK,
    const ushort* __restrict__ Bt, long sBt,
    const float* __restrict__ bias,
    float* __restrict__ Cf, ushort* __restrict__ Cb, long sC,
    const float* __restrict__ biasi,
    const float* __restrict__ FA, const float2* __restrict__ ST1,
    const float* __restrict__ WTp, const float* __restrict__ BTp,
    float2* __restrict__ partOut) {
    __shared__ ushort As[2][128 * 32];
    __shared__ ushort Bs[2][128 * 32];
    __shared__ float sc[4];
    const int tid = threadIdx.x;
    const int bl = blockIdx.z;
    const int m0 = blockIdx.x * 128, n0 = blockIdx.y * 128;
    const int N = gridDim.y * 128;
    const int lane = tid & 63, w = tid >> 6;
    const int wm = (w >> 1) * 64, wn = (w & 1) * 64;
    const int sr = tid >> 2, sk = (tid & 3) * 8;
    const int fr = lane & 15, fk = (lane >> 4) * 8;
    f32x4 acc[4][4] = {};
    const ushort* Ab0 = A0 + (long)bl * sA0;
    const ushort* Ab1 = (NPAIR == 2) ? A1 + (long)bl * sA1 : nullptr;
    const ushort* Bb = Bt + (long)bl * sBt;

    auto stage = [&](int buf, int k0) {
        const ushort* Asrc = Ab0; int kl = k0;
        if (NPAIR == 2 && k0 >= K0) { Asrc = Ab1; kl = k0 - K0; }
        gload16(&Asrc[(long)(m0 + sr) * lda + kl + sk],      &As[buf][sr * 32 + sk]);
        gload16(&Asrc[(long)(m0 + sr + 64) * lda + kl + sk], &As[buf][(sr + 64) * 32 + sk]);
        gload16(&Bb[(long)(n0 + sr) * KK + k0 + sk],         &Bs[buf][sr * 32 + sk]);
        gload16(&Bb[(long)(n0 + sr + 64) * KK + k0 + sk],    &Bs[buf][(sr + 64) * 32 + sk]);
    };
    auto compute = [&](int buf) {
        bf16x8 af[4], bg[4];
        #pragma unroll
        for (int i = 0; i < 4; i++) {
            af[i] = *(const bf16x8*)&As[buf][(wm + i * 16 + fr) * 32 + fk];
            bg[i] = *(const bf16x8*)&Bs[buf][(wn + i * 16 + fr) * 32 + fk];
        }
        #pragma unroll
        for (int i = 0; i < 4; i++)
            #pragma unroll
            for (int j = 0; j < 4; j++)
                acc[i][j] = __builtin_amdgcn_mfma_f32_16x16x32_bf16(af[i], bg[j], acc[i][j], 0, 0, 0);
    };

    stage(0, 0);
    __syncthreads();
    int cur = 0;
    for (int k0 = 32; k0 < KK; k0 += 32) {
        stage(cur ^ 1, k0);
        compute(cur);
        __syncthreads();
        cur ^= 1;
    }
    compute(cur);

    const int cn = lane & 15, rb = (lane >> 4) * 4;
    if (GLU == 1) {
        #pragma unroll
        for (int nt = 0; nt < 4; nt += 2) {
            int n1 = n0 + wn + nt * 16 + cn;
            int hcol = ((n1 >> 5) << 4) + cn;
            float b1 = biasi[n1], b2 = biasi[n1 + 16];
            #pragma unroll
            for (int i = 0; i < 4; i++) {
                #pragma unroll
                for (int r = 0; r < 4; r++) {
                    int m = m0 + wm + i * 16 + rb + r;
                    float g1 = acc[i][nt][r] + b1;
                    float g2 = acc[i][nt + 1][r] + b2;
                    float h = g1 / (1.f + __expf(-g2));
                    Cb[(long)bl * sC + (long)m * 256 + hcol] = f2b(h);
                }
            }
        }
    } else if (GLU == 2) {
        float2 st = ST1[bl];
        float ssum = 0.f, qsum = 0.f;
        #pragma unroll
        for (int j = 0; j < 4; j++) {
            int n = n0 + wn + j * 16 + cn;
            float bv = bias[n];
            #pragma unroll
            for (int i = 0; i < 4; i++) {
                #pragma unroll
                for (int r = 0; r < 4; r++) {
                    int m = m0 + wm + i * 16 + rb + r;
                    long idx = (long)bl * sC + (long)m * N + n;
                    float xn = (FA[idx] - st.x) * st.y;
                    float v = (acc[i][j][r] + bv + xn) * WTp[m * 256 + n] + BTp[m * 256 + n];
                    Cf[idx] = v;
                    ssum += v;
                    qsum += v * v;
                }
            }
        }
        ssum = block_sum256(ssum, sc);
        qsum = block_sum256(qsum, sc);
        if (tid == 0)
            partOut[bl * 16 + blockIdx.x * 2 + blockIdx.y] = make_float2(ssum, qsum);
    } else {
        #pragma unroll
        for (int j = 0; j < 4; j++) {
            int n = n0 + wn + j * 16 + cn;
            float bv = bias ? bias[n] : 0.f;
            #pragma unroll
            for (int i = 0; i < 4; i++) {
                #pragma unroll
                for (int r = 0; r < 4; r++) {
                    int m = m0 + wm + i * 16 + rb + r;
                    float v = acc[i][j][r] + bv;
                    long idx = (long)bl * sC + (long)m * N + n;
                    if (Cf) Cf[idx] = v;
                    if (Cb) Cb[idx] = f2b(v);
                }
            }
        }
    }
}

// ---------------- w1/w2 GEMV ----------------
__global__ __launch_bounds__(256) void k_dots(const ushort* __restrict__ X,
                                              const float* __restrict__ va,
                                              float* __restrict__ o1,
                                              float* __restrict__ o2) {
    int wid = threadIdx.x >> 6, lane = threadIdx.x & 63;
    long row = (long)blockIdx.x * 4 + wid;
    uint2 xv = *(const uint2*)(X + row * 256 + lane * 4);
    float x0 = b2f(xv.x), x1 = b2f(xv.x >> 16), x2 = b2f(xv.y), x3 = b2f(xv.y >> 16);
    float4 v1 = *(const float4*)&va[lane * 4];
    float4 v2 = *(const float4*)&va[256 + lane * 4];
    float s1 = x0 * v1.x + x1 * v1.y + x2 * v1.z + x3 * v1.w;
    float s2 = x0 * v2.x + x1 * v2.y + x2 * v2.z + x3 * v2.w;
    #pragma unroll
    for (int o = 32; o > 0; o >>= 1) { s1 += __shfl_xor(s1, o, 64); s2 += __shfl_xor(s2, o, 64); }
    if (lane == 0) { o1[row] = s1; o2[row] = s2; }
}

// ------- per-bl global max of w2 -------
__global__ __launch_bounds__(256) void k_w2max(const float* __restrict__ w2v,
                                               float* __restrict__ w2m) {
    __shared__ float sc[4];
    int bl = blockIdx.x;
    float4 v = *(const float4*)&w2v[(long)bl * 1024 + threadIdx.x * 4];
    float m = fmaxf(fmaxf(v.x, v.y), fmaxf(v.z, v.w));
    m = block_max256(m, sc);
    if (threadIdx.x == 0) w2m[bl] = m;
}

// ------- MFMA attention v8: barrier-free, exp-free inner loop -------
// exp2 is monotone: p = exp2(max(w1m+w2L, w1n+w2N)) = max(c1*E[j], c2*F[j])
// with E=exp2(w2*log2e), F=exp2(0.2*w2*log2e) precomputed per block, and
// c1=exp2(w1L-mrL), c2=exp2(0.2*w1L-mrL) per row. Inner p = 2 mul + 1 max.
// Mask via 4-entry LUT AND on packed bf16; row sums via MFMA vs all-ones B.
// FUSE=1: epilogue computes as*elu(out)+bs*gcn+x -> Af fp32 + LN partials.
template<int FUSE>
__global__ __launch_bounds__(256, 3) void k_attn_mf(
    const ushort* __restrict__ WhT,   // [48][256][1024] bf16
    const float* __restrict__ w1v, const float* __restrict__ w2v,
    const float* __restrict__ w2m,    // [48]
    const uint* __restrict__ maskw,   // [1024][32]
    ushort* __restrict__ outB,
    const float* __restrict__ gcn, const float* __restrict__ xf,
    const float* __restrict__ alpha,
    float* __restrict__ outF, float2* __restrict__ part) {
    __shared__ float w2E[1024];          // exp2(w2 * log2e)
    __shared__ float w2F[1024];          // exp2(0.2 * w2 * log2e)
    __shared__ uint msk[64 * 33];        // padded stride 33
    __shared__ uint mlut[4];             // 2-bit mask -> halfword AND pattern
    __shared__ float sc[4];
    constexpr float LOG2E = 1.4426950408889634f;
    int d = blockIdx.x;                  // 768 blocks
    int lidx = (d & 7) * 96 + (d >> 3);  // XCD-chunked: 6 bl per XCD
    int bl = lidx >> 4;
    int i0 = (lidx & 15) * 64;
    int tid = threadIdx.x;
    #pragma unroll
    for (int q = 0; q < 4; q++) {
        float v = w2v[(long)bl * 1024 + tid + q * 256];
        w2E[tid + q * 256] = fexp2(v * LOG2E);
        w2F[tid + q * 256] = fexp2(v * (0.2f * LOG2E));
    }
    if (tid < 4) mlut[tid] = ((tid & 1) ? 0x0000FFFFu : 0u) | ((tid & 2) ? 0xFFFF0000u : 0u);
    {   // mask staging: 2048 words, coalesced, padded stride
        const uint4* gm = (const uint4*)(maskw + (long)i0 * 32);
        uint4 ma = gm[tid * 2], mb = gm[tid * 2 + 1];
        int r0 = tid >> 2, w0 = (tid & 3) * 8;
        uint* mp = &msk[r0 * 33 + w0];
        mp[0] = ma.x; mp[1] = ma.y; mp[2] = ma.z; mp[3] = ma.w;
        mp[4] = mb.x; mp[5] = mb.y; mp[6] = mb.z; mp[7] = mb.w;
    }
    __syncthreads();
    const int lane = tid & 63, w = tid >> 6;
    const int wn = w * 64;
    const int fr = lane & 15, fg = lane >> 4, fk8 = fg * 8;
    const float w2mL = w2m[bl] * LOG2E;
    float c1[4], c2[4];
    #pragma unroll
    for (int mt = 0; mt < 4; mt++) {
        float w1L = w1v[(long)bl * 1024 + i0 + mt * 16 + fr] * LOG2E;
        float e0 = w1L + w2mL;
        float mrL = fmaxf(e0, 0.2f * e0);          // = log2e * leaky(w1+w2max) >= all scores
        c1[mt] = fexp2(w1L - mrL);
        c2[mt] = fexp2(0.2f * w1L - mrL);
    }
    f32x4 acc[4][4] = {};
    f32x4 acc_s[4] = {};
    u32x4 ov; ov[0] = ov[1] = ov[2] = ov[3] = 0x3F803F80u;   // bf16 1.0 pairs
    const bf16x8 onesf = __builtin_bit_cast(bf16x8, ov);
    const ushort* bp = WhT + (long)bl * SLAB;
    #pragma unroll 1
    for (int ks = 0; ks < 32; ks++) {
        bf16x8 bg[4];
        #pragma unroll
        for (int nt = 0; nt < 4; nt++)
            bg[nt] = *(const bf16x8*)&bp[(long)(wn + nt * 16 + fr) * 1024 + ks * 32 + fk8];
        float4 ea = *(const float4*)&w2E[ks * 32 + fk8];
        float4 eb = *(const float4*)&w2E[ks * 32 + fk8 + 4];
        float4 fa = *(const float4*)&w2F[ks * 32 + fk8];
        float4 fb = *(const float4*)&w2F[ks * 32 + fk8 + 4];
        #pragma unroll
        for (int mt = 0; mt < 4; mt++) {
            uint mby = (msk[(mt * 16 + fr) * 33 + ks] >> (fg * 8)) & 0xffu;
            float p0 = fmaxf(c1[mt] * ea.x, c2[mt] * fa.x);
            float p1 = fmaxf(c1[mt] * ea.y, c2[mt] * fa.y);
            float p2 = fmaxf(c1[mt] * ea.z, c2[mt] * fa.z);
            float p3 = fmaxf(c1[mt] * ea.w, c2[mt] * fa.w);
            float p4 = fmaxf(c1[mt] * eb.x, c2[mt] * fb.x);
            float p5 = fmaxf(c1[mt] * eb.y, c2[mt] * fb.y);
            float p6 = fmaxf(c1[mt] * eb.z, c2[mt] * fb.z);
            float p7 = fmaxf(c1[mt] * eb.w, c2[mt] * fb.w);
            u32x4 av;
            av[0] = pack2(p0, p1) & mlut[mby & 3];
            av[1] = pack2(p2, p3) & mlut[(mby >> 2) & 3];
            av[2] = pack2(p4, p5) & mlut[(mby >> 4) & 3];
            av[3] = pack2(p6, p7) & mlut[(mby >> 6) & 3];
            bf16x8 af = __builtin_bit_cast(bf16x8, av);
            acc_s[mt] = __builtin_amdgcn_mfma_f32_16x16x32_bf16(af, onesf, acc_s[mt], 0, 0, 0);
            #pragma unroll
            for (int nt = 0; nt < 4; nt++)
                acc[mt][nt] = __builtin_amdgcn_mfma_f32_16x16x32_bf16(
                    af, bg[nt], acc[mt][nt], 0, 0, 0);
        }
    }
    float as = 0.f, bs = 0.f, ssum = 0.f, qsum = 0.f;
    if (FUSE) { as = 1.f / (1.f + __expf(-alpha[0])); bs = 1.f - as; }
    #pragma unroll
    for (int mt = 0; mt < 4; mt++) {
        #pragma unroll
        for (int r = 0; r < 4; r++) {
            float si = 1.f / acc_s[mt][r];          // own row's sum — no cross-lane
            int i = mt * 16 + fg * 4 + r;
            #pragma unroll
            for (int nt = 0; nt < 4; nt++) {
                int c = wn + nt * 16 + fr;
                float v = acc[mt][nt][r] * si;
                v = (v > 0.f) ? v : __expf(v) - 1.f;       // elu
                long idx = (long)bl * SLAB + (long)(i0 + i) * 256 + c;
                if (FUSE) {
                    float fv = as * v + bs * gcn[idx] + xf[idx];
                    outF[idx] = fv;
                    ssum += fv;
                    qsum += fv * fv;
                } else {
                    outB[idx] = f2b(v);
                }
            }
        }
    }
    if (FUSE) {
        ssum = block_sum256(ssum, sc);
        qsum = block_sum256(qsum, sc);
        if (tid == 0) part[bl * 16 + (lidx & 15)] = make_float2(ssum, qsum);
    }
}

// ------- stats from 16 partials per slab -------
__global__ void k_stats16(const float2* __restrict__ part, float2* __restrict__ stats) {
    int bl = blockIdx.x, t = threadIdx.x;
    float s = 0.f, q = 0.f;
    if (t < 16) { float2 v = part[bl * 16 + t]; s = v.x; q = v.y; }
    #pragma unroll
    for (int o = 8; o > 0; o >>= 1) { s += __shfl_xor(s, o, 64); q += __shfl_xor(q, o, 64); }
    if (t == 0) {
        float mean = s / (float)SLAB;
        float var = q / (float)SLAB - mean * mean;
        stats[bl] = make_float2(mean, 1.f / sqrtf(var + 1e-5f));
    }
}

// ------- LN apply, bf16 out only -------
__global__ __launch_bounds__(256) void k_ln_apply(const float4* __restrict__ x,
                                                  const float2* __restrict__ stats,
                                                  ushort* __restrict__ ob) {
    long i = (long)blockIdx.x * 256 + threadIdx.x;
    int bl = (int)(i >> 16);
    float2 st = stats[bl];
    float4 v = x[i];
    uint2 ow;
    ow.x = pack2((v.x - st.x) * st.y, (v.y - st.x) * st.y);
    ow.y = pack2((v.z - st.x) * st.y, (v.w - st.x) * st.y);
    ((uint2*)ob)[i] = ow;
}

// ------- final normalize + transpose back to [b][c][n][l] -------
__global__ __launch_bounds__(256) void k_out(const float* __restrict__ x,
                                             const float2* __restrict__ stats,
                                             float* __restrict__ out) {
    int n = blockIdx.x, b = blockIdx.y, c = threadIdx.x;
    float v[12];
    #pragma unroll
    for (int l = 0; l < 12; l++) {
        float2 st = stats[b * 12 + l];
        float t = x[(long)(b * 12 + l) * SLAB + (long)n * 256 + c];
        v[l] = (t - st.x) * st.y;
    }
    float4* op = (float4*)(out + ((long)(b * 256 + c) * 1024 + n) * 12);
    op[0] = make_float4(v[0], v[1], v[2], v[3]);
    op[1] = make_float4(v[4], v[5], v[6], v[7]);
    op[2] = make_float4(v[8], v[9], v[10], v[11]);
}

// =================================================================
extern "C" void kernel_launch(void* const* d_in, const int* in_sizes, int n_in,
                              void* d_out, int out_size, void* d_ws, size_t ws_size,
                              hipStream_t stream) {
    (void)in_sizes; (void)n_in; (void)out_size; (void)ws_size;
    const float* x_in = (const float*)d_in[0];
    const int*   dg   = (const int*)d_in[1];
    const float* nv1  = (const float*)d_in[2];
    const float* nv2  = (const float*)d_in[3];
    const float* Wmlp = (const float*)d_in[4];
    const float* bmlp = (const float*)d_in[5];
    const float* Wg0  = (const float*)d_in[6];
    const float* ag0  = (const float*)d_in[7];
    const float* Wgo  = (const float*)d_in[8];
    const float* ago  = (const float*)d_in[9];
    const float* Wg1  = (const float*)d_in[10];
    const float* bg1  = (const float*)d_in[11];
    const float* Wg2  = (const float*)d_in[12];
    const float* bg2  = (const float*)d_in[13];
    const float* Wg3  = (const float*)d_in[14];
    const float* bg3  = (const float*)d_in[15];
    const float* alpha = (const float*)d_in[16];
    const float* wgt  = (const float*)d_in[17];
    const float* bia  = (const float*)d_in[18];
    float* out = (float*)d_out;

    // ---- workspace (~208 MB; Af aliases the dead U1+U2 region) ----
    float* XTf = (float*)d_ws;          // fp32 x_in copy
    float* Bf  = XTf + TOT;             // fp32 gcn; later final pre-LN
    ushort* U1 = (ushort*)(Bf + TOT);   // Xb bf16
    ushort* U2 = U1 + TOT;              // XTT; later g (attn1 out)
    float* Af  = (float*)U1;            // fp32 fuse output, live after U1/U2 dead
    ushort* U3 = U2 + TOT;              // x1b; later xn bf16
    ushort* U4 = U3 + TOT;              // WhT; later h bf16
    ushort* ADPB = U4 + TOT;            // [1024][1024]
    ushort* WMLPB = ADPB + (long)1024 * 1024;
    ushort* WG0T = WMLPB + 131072;
    ushort* WGOT = WG0T + 65536;
    ushort* WGIB = WGOT + 65536;        // [512][256] interleaved g1/g2
    ushort* WG3B = WGIB + 131072;
    float* BIASI = (float*)(WG3B + 65536);  // 512
    float* VA = BIASI + 512;                // 1024
    float* W1V = VA + 1024;
    float* W2V = W1V + 49152;
    float* W2M = W2V + 49152;               // 48 (+pad)
    uint* MASKW = (uint*)(W2M + 64);        // 32768
    float2* PART = (float2*)(MASKW + 32768); // [48][16]
    float2* STATS1 = PART + 48 * 16;
    float2* STATS2 = STATS1 + 48;
    float* WT = (float*)(STATS2 + 48);
    float* BT2 = WT + SLAB;

    dim3 blk(256);
    // prep
    k_wt2<<<dim3(4, 4, 2), blk, 0, stream>>>(Wg0, WG0T, Wgo, WGOT);
    k_wconv<<<512, blk, 0, stream>>>(Wmlp, WMLPB);
    k_wconv<<<256, blk, 0, stream>>>(Wg3, WG3B);
    k_wgi<<<512, blk, 0, stream>>>(Wg1, bg1, Wg2, bg2, WGIB, BIASI);
    k_va<<<256, blk, 0, stream>>>(Wg0, ag0, VA);
    k_va<<<256, blk, 0, stream>>>(Wgo, ago, VA + 512);
    k_wtprep<<<1024, blk, 0, stream>>>(wgt, bia, WT, BT2);
    k_adp<<<1024, blk, 0, stream>>>(nv1, nv2, ADPB);
    k_maskpack<<<128, blk, 0, stream>>>(dg, MASKW);
    k_tin<<<dim3(192, 4, 4), blk, 0, stream>>>(x_in, U1, XTf);
    k_xtt<<<dim3(16, 4, 48), blk, 0, stream>>>(U1, U2);
    // x1 = adp @ x  (Bt = XTT) -> U3 bf16
    k_bgemm<1, 0><<<dim3(8, 2, 48), blk, 0, stream>>>(ADPB, 0, nullptr, 0, 1024, 0, 1024,
        U2, SLAB, nullptr, nullptr, U3, SLAB, nullptr,
        nullptr, nullptr, nullptr, nullptr, nullptr);
    // gcn = [x|x1] @ Wmlp(o,c) + b -> Bf fp32
    k_bgemm<2, 0><<<dim3(8, 2, 48), blk, 0, stream>>>(U1, SLAB, U3, SLAB, 256, 256, 512,
        WMLPB, 0, bmlp, Bf, nullptr, SLAB, nullptr,
        nullptr, nullptr, nullptr, nullptr, nullptr);
    // GAT layer 1
    k_dots<<<12288, blk, 0, stream>>>(U1, VA, W1V, W2V);
    k_w2max<<<48, blk, 0, stream>>>(W2V, W2M);
    k_bgemm<1, 0><<<dim3(2, 8, 48), blk, 0, stream>>>(WG0T, 0, nullptr, 0, 256, 0, 256,
        U1, SLAB, nullptr, nullptr, U4, SLAB, nullptr,
        nullptr, nullptr, nullptr, nullptr, nullptr);
    k_attn_mf<0><<<768, blk, 0, stream>>>(U4, W1V, W2V, W2M, MASKW, U2,
                                          nullptr, nullptr, nullptr, nullptr, nullptr);
    // GAT layer 2
    k_dots<<<12288, blk, 0, stream>>>(U2, VA + 512, W1V, W2V);
    k_w2max<<<48, blk, 0, stream>>>(W2V, W2M);
    k_bgemm<1, 0><<<dim3(2, 8, 48), blk, 0, stream>>>(WGOT, 0, nullptr, 0, 256, 0, 256,
        U2, SLAB, nullptr, nullptr, U4, SLAB, nullptr,
        nullptr, nullptr, nullptr, nullptr, nullptr);
    // attn2 fused epilogue: Af = as*gat + bs*gcn + x, + LN1 partials
    k_attn_mf<1><<<768, blk, 0, stream>>>(U4, W1V, W2V, W2M, MASKW, nullptr,
                                          Bf, XTf, alpha, Af, PART);
    k_stats16<<<48, 64, 0, stream>>>(PART, STATS1);
    k_ln_apply<<<12288, blk, 0, stream>>>((const float4*)Af, STATS1, U3);
    // GLU pair GEMM (interleaved) -> U4 h bf16
    k_bgemm<1, 1><<<dim3(8, 4, 48), blk, 0, stream>>>(U3, SLAB, nullptr, 0, 256, 0, 256,
        WGIB, 0, nullptr, nullptr, U4, SLAB, BIASI,
        nullptr, nullptr, nullptr, nullptr, nullptr);
    // glu3 GEMM + finpre + LN2 partials -> Bf, PART
    k_bgemm<1, 2><<<dim3(8, 2, 48), blk, 0, stream>>>(U4, SLAB, nullptr, 0, 256, 0, 256,
        WG3B, 0, bg3, Bf, nullptr, SLAB, nullptr,
        Af, STATS1, WT, BT2, PART);
    k_stats16<<<48, 64, 0, stream>>>(PART, STATS2);
    k_out<<<dim3(1024, 4), blk, 0, stream>>>(Bf, STATS2, out);
}